// Round 7
// baseline (325.321 us; speedup 1.0000x reference)
//
#include <hip/hip_runtime.h>
#include <hip/hip_bf16.h>

#define NN    200000
#define EE    3200000
#define DDIMC 768

#define NI4   800000    // EE/4 int4s
#define HTH   1024      // histogram block threads
#define PARTW (25 * 12 * 8192)   // legacy region size (k_hist partials live here)

// hcol: packed 2x16-bit counts, 32768 nodes / 64KB LDS, 7 passes
// CC MUST be a multiple of 8: same-j blocks (blockIdx = b*CC + j) share one
// XCD's L2 (blockIdx%8 == j%8) -> the NB-way edge re-read is L2-served AND
// the per-copy merge atomics (copy = j&7) are XCD-LOCAL (no cross-XCD
// memory-side RMW -- that was the R4-R6 63us floor: 30MB WRITE_SIZE for
// 850KB of data).
#define BSZC  32768
#define BSHC  15
#define NBC   7
#define CCC   72        // 7*72 = 504 blocks (~2/CU, 72%8==0)
#define DEGC  (NBC * (BSZC / 2))     // 114688 words per copy
// hrow: float, 16384 nodes / 64KB LDS, 13 passes
#define BSZR  16384
#define BSHR  14
#define NBR   13
#define CCR   40        // 13*40 = 520 blocks (~2/CU, 40%8==0)
#define PARTC (NBR * BSZR)           // 212992 words per copy

#define NDBLK 782       // ceil(NN/256)
#define XBLOCKS 1024
#define CAPL  4096

#define HB    64        // score-hist partial blocks (NN/HB = 3125 exact)
#define HW    32768     // packed u32 words (2x16-bit counts) = 65536 buckets

// ---- workspace layout (word offsets) ----
// [0 ..) region is time-multiplexed:
//   degm8  = 8 copies x DEGC  = 917504 words   (k_hcol -> k_redA)
//   partm8 = 8 copies x PARTC = 1703936 words  (k_hrow -> k_redB, zeroed after redA)
//   k_hist partials = HB*HW   = 2097152 words  (after redB)
// all < PARTW, so everything from P_HIST up is untouched.
#define P_PART  0
#define P_DEGM  0
#define P_PARTM 0
#define ZLEN1   (8 * DEGC)               // 917504
#define ZLEN2   (8 * PARTC)              // 1703936
#define P_HIST  PARTW                    // 65536 i32 (fully overwritten by k_redH)
#define P_CANDN (P_HIST + 65536)         // 8 (zeroed)
#define P_S8    (P_CANDN + 8)            // 512 (zeroed)
#define ZERO_LEN (8 + 512)               // from P_CANDN
#define P_FLAG  (P_S8 + 512)
#define P_THR   (P_FLAG + 8)
#define P_SV    (P_THR + 8)
#define P_D     (P_SV + 64)
#define P_DIS   (P_D + 256)
#define P_C     (P_DIS + NN)
#define P_SCORE (P_C + NN)
#define P_CKEY  (P_SCORE + NN)
#define P_CIDX  (P_CKEY + 4096)
#define P_XT    (P_CIDX + 4096)
#define P_WW    (P_XT + 4096)
#define P_G     (P_WW + 4096)            // 256 f32
#define P_LNV   (P_G + 256)              // 512 f32
#define P_H1    (P_LNV + 512)            // 256 f32

// ---- helpers (proven) ----
__device__ __forceinline__ float ldf(const void* p, int i, int bf) {
  if (bf) return __bfloat162float(((const __hip_bfloat16*)p)[i]);
  return ((const float*)p)[i];
}
__device__ __forceinline__ void stf(void* p, int i, float v, int bf) {
  if (bf) ((__hip_bfloat16*)p)[i] = __float2bfloat16(v);
  else ((float*)p)[i] = v;
}
__device__ __forceinline__ float bfu(unsigned u) {   // low 16 bits -> bf16 value
  return __uint_as_float(u << 16);
}
__device__ __forceinline__ float wsum(float v) {
#pragma unroll
  for (int m = 32; m >= 1; m >>= 1) v += __shfl_xor(v, m, 64);
  return v;
}
__device__ __forceinline__ int wsumi(int v) {
#pragma unroll
  for (int m = 32; m >= 1; m >>= 1) v += __shfl_xor(v, m, 64);
  return v;
}
__device__ __forceinline__ unsigned sortkey(float f) {
  unsigned u = __float_as_uint(f);
  return (u & 0x80000000u) ? ~u : (u | 0x80000000u);
}

// ---- dtype detector (proven) ----
__global__ void k_detect(const unsigned short* x16, int* flag) {
  __shared__ int cnt;
  if (threadIdx.x == 0) cnt = 0;
  __syncthreads();
  int ok = 0;
  for (int k = threadIdx.x; k < 512; k += 256) {
    unsigned short u = x16[2 * k];
    int e = (u >> 7) & 0xFF;
    if (u == 0 || (e >= 100 && e <= 150)) ok++;
  }
  atomicAdd(&cnt, ok);
  __syncthreads();
  if (threadIdx.x == 0) flag[0] = (cnt >= 400) ? 1 : 0;
}

// ---- degree histogram: XCD-local merge (copy = j&7) ----
__global__ void __launch_bounds__(HTH) k_hcol(const int* __restrict__ col,
                                              unsigned* __restrict__ degm) {
  __shared__ unsigned lh[BSZC / 2];
  int t = threadIdx.x;
  int b = blockIdx.x / CCC, j = blockIdx.x % CCC;
  for (int k = t; k < BSZC / 2; k += HTH) lh[k] = 0u;
  __syncthreads();
  int base = b << BSHC;
  const int4* c4 = (const int4*)col;
  const int stride = CCC * HTH;
  for (int i = j * HTH + t; i < NI4; i += 2 * stride) {
    int4 v0 = c4[i];
    int i2 = i + stride;
    int4 v1; v1.x = v1.y = v1.z = v1.w = -1;   // sentinel: fails every bucket test
    if (i2 < NI4) v1 = c4[i2];
    {
      int a0 = v0.x - base, a1 = v0.y - base, a2 = v0.z - base, a3 = v0.w - base;
      if ((unsigned)a0 < (unsigned)BSZC) atomicAdd(&lh[a0 >> 1], 1u << ((a0 & 1) * 16));
      if ((unsigned)a1 < (unsigned)BSZC) atomicAdd(&lh[a1 >> 1], 1u << ((a1 & 1) * 16));
      if ((unsigned)a2 < (unsigned)BSZC) atomicAdd(&lh[a2 >> 1], 1u << ((a2 & 1) * 16));
      if ((unsigned)a3 < (unsigned)BSZC) atomicAdd(&lh[a3 >> 1], 1u << ((a3 & 1) * 16));
    }
    {
      int a0 = v1.x - base, a1 = v1.y - base, a2 = v1.z - base, a3 = v1.w - base;
      if ((unsigned)a0 < (unsigned)BSZC) atomicAdd(&lh[a0 >> 1], 1u << ((a0 & 1) * 16));
      if ((unsigned)a1 < (unsigned)BSZC) atomicAdd(&lh[a1 >> 1], 1u << ((a1 & 1) * 16));
      if ((unsigned)a2 < (unsigned)BSZC) atomicAdd(&lh[a2 >> 1], 1u << ((a2 & 1) * 16));
      if ((unsigned)a3 < (unsigned)BSZC) atomicAdd(&lh[a3 >> 1], 1u << ((a3 & 1) * 16));
    }
  }
  __syncthreads();
  // merge into XCD-local copy: all writers of copy (j&7) run on XCD (j&7),
  // so these atomics stay in that XCD's L2 (no cross-XCD coherence traffic).
  unsigned* dst = degm + (size_t)(j & 7) * DEGC + (size_t)b * (BSZC / 2);
  for (int k = t; k < BSZC / 2; k += HTH) {
    unsigned v = lh[k];
    if (v) atomicAdd(&dst[k], v);
  }
}

// ---- reduce: dis from 8 packed degm copies; doc matvec on extra blocks ----
__global__ void k_redA(const unsigned* __restrict__ degm, float* __restrict__ dis,
                       const void* docf, const void* dw, const void* db,
                       float* __restrict__ d, const int* flagp) {
  if (blockIdx.x < NDBLK) {
    int i = blockIdx.x * 256 + threadIdx.x;
    if (i < NN) {
      int sh = (i & 1) * 16;
      int deg = 1;
#pragma unroll
      for (int p = 0; p < 8; p++) {
        unsigned w_ = degm[(size_t)p * DEGC + (i >> 1)];
        deg += (int)((w_ >> sh) & 0xffffu);
      }
      dis[i] = rsqrtf((float)deg);
    }
  } else {
    int flag = flagp[0];
    int o = (blockIdx.x - NDBLK) * 4 + (threadIdx.x >> 6);
    int lane = threadIdx.x & 63;
    float acc = 0.f;
    for (int k = lane; k < DDIMC; k += 64) acc += ldf(docf, k, flag) * ldf(dw, o * DDIMC + k, flag);
    acc = wsum(acc);
    if (lane == 0) d[o] = fmaxf(acc + ldf(db, o, flag), 0.0f);
  }
}

// ---- weighted row histogram: XCD-local merge (copy = j&7) ----
__global__ void __launch_bounds__(HTH) k_hrow(const int* __restrict__ row, const int* __restrict__ col,
                                              const float* __restrict__ dis,
                                              float* __restrict__ partm) {
  __shared__ float lh[BSZR];
  int t = threadIdx.x;
  int b = blockIdx.x / CCR, j = blockIdx.x % CCR;
  for (int k = t; k < BSZR; k += HTH) lh[k] = 0.f;
  __syncthreads();
  int base = b << BSHR;
  const int4* r4 = (const int4*)row;
  const int4* c4 = (const int4*)col;
  const int stride = CCR * HTH;
  for (int i = j * HTH + t; i < NI4; i += 2 * stride) {
    int4 r0 = r4[i];
    int4 c0 = c4[i];
    int i2 = i + stride;
    int4 r1; r1.x = r1.y = r1.z = r1.w = -1;   // sentinel rows: never in-bucket
    int4 c1; c1.x = c1.y = c1.z = c1.w = 0;
    if (i2 < NI4) { r1 = r4[i2]; c1 = c4[i2]; }
    {
      int a0 = r0.x - base, a1 = r0.y - base, a2 = r0.z - base, a3 = r0.w - base;
      if ((unsigned)a0 < (unsigned)BSZR) atomicAdd(&lh[a0], dis[c0.x]);
      if ((unsigned)a1 < (unsigned)BSZR) atomicAdd(&lh[a1], dis[c0.y]);
      if ((unsigned)a2 < (unsigned)BSZR) atomicAdd(&lh[a2], dis[c0.z]);
      if ((unsigned)a3 < (unsigned)BSZR) atomicAdd(&lh[a3], dis[c0.w]);
    }
    {
      int a0 = r1.x - base, a1 = r1.y - base, a2 = r1.z - base, a3 = r1.w - base;
      if ((unsigned)a0 < (unsigned)BSZR) atomicAdd(&lh[a0], dis[c1.x]);
      if ((unsigned)a1 < (unsigned)BSZR) atomicAdd(&lh[a1], dis[c1.y]);
      if ((unsigned)a2 < (unsigned)BSZR) atomicAdd(&lh[a2], dis[c1.z]);
      if ((unsigned)a3 < (unsigned)BSZR) atomicAdd(&lh[a3], dis[c1.w]);
    }
  }
  __syncthreads();
  float* dst = partm + (size_t)(j & 7) * PARTC + (size_t)b * BSZR;
  for (int k = t; k < BSZR; k += HTH) {
    float v = lh[k];
    if (v != 0.f) atomicAdd(&dst[k], v);
  }
}

// ---- reduce: c_i = dis_i * (sum of 8 partm copies)_i + dis_i^2 ----
__global__ void k_redB(const float* __restrict__ partm, const float* __restrict__ dis,
                       float* __restrict__ c) {
  int i = blockIdx.x * 256 + threadIdx.x;
  if (i < NN) {
    float s = 0.f;
#pragma unroll
    for (int p = 0; p < 8; p++) s += partm[(size_t)p * PARTC + i];
    float dv = dis[i];
    c[i] = dv * s + dv * dv;
  }
}

// ---- fused x pass (proven R2): pure stream, score + column accumulator ----
__global__ void k_x(const void* x, const void* pw, const float* __restrict__ c,
                    float* __restrict__ score,
                    float* __restrict__ s8, const int* flagp) {
  __shared__ float sred[4][64];
  int flag = flagp[0];
  int t = threadIdx.x;
  int lane = t & 63;
  int w = t >> 6;
  int wid = (blockIdx.x * 256 + t) >> 6;
  int nw = (gridDim.x * 256) >> 6;

  if (flag) {
    int g  = lane >> 3;        // row subgroup 0..7
    int c0 = (lane & 7) * 8;   // column base for this lane
    float pwv[8];
#pragma unroll
    for (int j = 0; j < 8; j++) pwv[j] = ldf(pw, c0 + j, 1);
    float s = 0.f;
#pragma unroll
    for (int j = 0; j < 8; j++) s += pwv[j] * pwv[j];
    float inv = 1.0f / sqrtf(wsum(s) * 0.125f);   // each column counted 8x
    float sacc[8] = {0.f, 0.f, 0.f, 0.f, 0.f, 0.f, 0.f, 0.f};
    const uint4* x4 = (const uint4*)x;
    for (int r0 = wid * 8; r0 < NN; r0 += nw * 8) {   // NN % 8 == 0
      int r = r0 + g;
      uint4 u = x4[r * 8 + (lane & 7)];               // contiguous 1KiB/wave
      float xv[8] = { bfu(u.x & 0xffff), bfu(u.x >> 16),
                      bfu(u.y & 0xffff), bfu(u.y >> 16),
                      bfu(u.z & 0xffff), bfu(u.z >> 16),
                      bfu(u.w & 0xffff), bfu(u.w >> 16) };
      float dot = 0.f;
#pragma unroll
      for (int j = 0; j < 8; j++) dot += xv[j] * pwv[j];
      dot += __shfl_xor(dot, 1, 64);
      dot += __shfl_xor(dot, 2, 64);
      dot += __shfl_xor(dot, 4, 64);
      float cr = c[r];
#pragma unroll
      for (int j = 0; j < 8; j++) sacc[j] += cr * xv[j];
      if ((lane & 7) == 0) score[r] = dot * inv;
    }
#pragma unroll
    for (int j = 0; j < 8; j++) {
      sacc[j] += __shfl_xor(sacc[j], 8, 64);
      sacc[j] += __shfl_xor(sacc[j], 16, 64);
      sacc[j] += __shfl_xor(sacc[j], 32, 64);
    }
    if (lane < 8) {
#pragma unroll
      for (int j = 0; j < 8; j++) sred[w][lane * 8 + j] = sacc[j];
    }
  } else {
    int g  = lane >> 4;        // row subgroup 0..3
    int c0 = (lane & 15) * 4;  // column base
    float pwv[4];
#pragma unroll
    for (int j = 0; j < 4; j++) pwv[j] = ((const float*)pw)[c0 + j];
    float s = 0.f;
#pragma unroll
    for (int j = 0; j < 4; j++) s += pwv[j] * pwv[j];
    float inv = 1.0f / sqrtf(wsum(s) * (1.f / 16.f));  // each column counted 16x
    float sacc[4] = {0.f, 0.f, 0.f, 0.f};
    const float4* x4 = (const float4*)x;
    for (int r0 = wid * 4; r0 < NN; r0 += nw * 4) {    // NN % 4 == 0
      int r = r0 + g;
      float4 v = x4[r * 16 + (lane & 15)];             // contiguous 1KiB/wave
      float xv[4] = { v.x, v.y, v.z, v.w };
      float dot = 0.f;
#pragma unroll
      for (int j = 0; j < 4; j++) dot += xv[j] * pwv[j];
      dot += __shfl_xor(dot, 1, 64);
      dot += __shfl_xor(dot, 2, 64);
      dot += __shfl_xor(dot, 4, 64);
      dot += __shfl_xor(dot, 8, 64);
      float cr = c[r];
#pragma unroll
      for (int j = 0; j < 4; j++) sacc[j] += cr * xv[j];
      if ((lane & 15) == 0) score[r] = dot * inv;
    }
#pragma unroll
    for (int j = 0; j < 4; j++) {
      sacc[j] += __shfl_xor(sacc[j], 16, 64);
      sacc[j] += __shfl_xor(sacc[j], 32, 64);
    }
    if (lane < 16) {
#pragma unroll
      for (int j = 0; j < 4; j++) sred[w][lane * 4 + j] = sacc[j];
    }
  }
  __syncthreads();
  if (w == 0)
    atomicAdd(&s8[(blockIdx.x & 7) * 64 + lane],
              sred[0][lane] + sred[1][lane] + sred[2][lane] + sred[3][lane]);
}

// ---- LDS-privatized full-resolution score histogram (proven R2) ----
__global__ void __launch_bounds__(1024) k_hist(const float* __restrict__ score,
                                               unsigned* __restrict__ part) {
  __shared__ unsigned lh[HW];
  int t = threadIdx.x;
  for (int k = t; k < HW; k += 1024) lh[k] = 0u;
  __syncthreads();
  int r0 = blockIdx.x * (NN / HB);
  int r1 = r0 + (NN / HB);
  for (int i = r0 + t; i < r1; i += 1024) {
    unsigned b = sortkey(score[i]) >> 16;
    atomicAdd(&lh[b >> 1], 1u << ((b & 1) * 16));
  }
  __syncthreads();
  unsigned* dst = part + (size_t)blockIdx.x * HW;
  for (int k = t; k < HW; k += 1024) dst[k] = lh[k];
}

// ---- sum HB packed partials -> hist (proven R2) ----
__global__ void k_redH(const unsigned* __restrict__ part, int* __restrict__ hist) {
  int w = blockIdx.x * 256 + threadIdx.x;   // 0..HW-1, grid 128 blocks
  unsigned lo = 0, hi = 0;
  for (int b = 0; b < HB; b++) {
    unsigned v = part[(size_t)b * HW + w];
    lo += v & 0xffffu;
    hi += v >> 16;
  }
  hist[2 * w]     = (int)lo;
  hist[2 * w + 1] = (int)hi;
}

// ---- threshold (proven) ----
__global__ void k_thresh(const int* __restrict__ hist, int* __restrict__ thrB,
                         const float* __restrict__ s8, float* __restrict__ svec) {
  __shared__ int part[256];
  __shared__ int segl[256];
  __shared__ int res2[2];
  int t = threadIdx.x, w = t >> 6, lane = t & 63;
  if (t < 64) {
    float a = 0.f;
    for (int r = 0; r < 8; r++) a += s8[r * 64 + t];
    svec[t] = a;
  }
  for (int m = w; m < 256; m += 4) {
    const int* hb = &hist[m * 256];
    int a = hb[lane] + hb[lane + 64] + hb[lane + 128] + hb[lane + 192];
    a = wsumi(a);
    if (lane == 0) part[m] = a;
  }
  __syncthreads();
  if (t == 0) {
    int acc = 0, seg = 0, above = 0;
    for (int b = 255; b >= 0; b--) {
      if (acc + part[b] >= 64) { seg = b; above = acc; break; }
      acc += part[b];
    }
    res2[0] = seg; res2[1] = above;
  }
  __syncthreads();
  segl[t] = hist[res2[0] * 256 + t];
  __syncthreads();
  if (t == 0) {
    int acc = res2[1], B = res2[0] * 256;
    for (int j = 255; j >= 0; j--) {
      acc += segl[j];
      if (acc >= 64) { B = res2[0] * 256 + j; break; }
    }
    thrB[0] = B;
  }
}

// ---- collect (proven) ----
__global__ void k_collect(const float* __restrict__ score, const int* __restrict__ thrB,
                          int* __restrict__ candn, unsigned* __restrict__ ckey,
                          int* __restrict__ cidx) {
  int i = blockIdx.x * blockDim.x + threadIdx.x;
  if (i >= NN) return;
  unsigned u = sortkey(score[i]);
  if ((int)(u >> 16) >= thrB[0]) {
    int p = atomicAdd(candn, 1);
    if (p < CAPL) { ckey[p] = u; cidx[p] = i; }
  }
}

// ---- top-64 (R7: 1024 threads, 4x faster serial rank loop) ----
__global__ void __launch_bounds__(1024) k_top(const int* __restrict__ candn,
                      const unsigned* __restrict__ ckey,
                      const int* __restrict__ cidx, const void* x,
                      float* __restrict__ xt, const int* flagp) {
  __shared__ unsigned long long keys[CAPL];
  __shared__ int perm[64];
  __shared__ float ts[64];
  int flag = flagp[0];
  int t = threadIdx.x;
  int M = candn[0];
  if (M > CAPL) M = CAPL;
  for (int j = t; j < M; j += 1024)
    keys[j] = (((unsigned long long)ckey[j]) << 32) |
              (unsigned long long)(0xFFFFFFFFu - (unsigned)cidx[j]);
  __syncthreads();
  for (int j = t; j < M; j += 1024) {
    unsigned long long k = keys[j];
    int rank = 0;
    for (int i = 0; i < M; i++) rank += (keys[i] > k) ? 1 : 0;
    if (rank < 64) {
      unsigned ku = (unsigned)(k >> 32);
      unsigned idx = 0xFFFFFFFFu - (unsigned)(k & 0xFFFFFFFFu);
      perm[rank] = (int)idx;
      unsigned bits = (ku & 0x80000000u) ? (ku ^ 0x80000000u) : ~ku;
      ts[rank] = tanhf(__uint_as_float(bits));
    }
  }
  __syncthreads();
  for (int q = t; q < 4096; q += 1024) {
    int j = q >> 6, f = q & 63;
    xt[q] = ldf(x, perm[j] * 64 + f, flag) * ts[j];
  }
}

// ---- GRU (proven round-0 rework): coalesced staging, LDS-side transpose ----
#define GS 193
__device__ __forceinline__ void stage_w(const void* src, float* dst, int flag, int t) {
  if (flag) {
    const uint4* s4 = (const uint4*)src;          // 12288 bf16 = 1536 uint4
    for (int k = t; k < 1536; k += 256) {
      uint4 u = s4[k];
      int e = k << 3; int o = e >> 6, f = e & 63; // 8 elems share o, f..f+7
      float* d = &dst[f * GS + o];
      d[0]      = bfu(u.x & 0xffff); d[GS]     = bfu(u.x >> 16);
      d[2 * GS] = bfu(u.y & 0xffff); d[3 * GS] = bfu(u.y >> 16);
      d[4 * GS] = bfu(u.z & 0xffff); d[5 * GS] = bfu(u.z >> 16);
      d[6 * GS] = bfu(u.w & 0xffff); d[7 * GS] = bfu(u.w >> 16);
    }
  } else {
    const float4* s4 = (const float4*)src;        // 12288 f32 = 3072 float4
    for (int k = t; k < 3072; k += 256) {
      float4 v = s4[k];
      int e = k << 2; int o = e >> 6, f = e & 63; // 4 elems share o, f..f+3
      float* d = &dst[f * GS + o];
      d[0] = v.x; d[GS] = v.y; d[2 * GS] = v.z; d[3 * GS] = v.w;
    }
  }
}

__global__ void k_gru(const float* __restrict__ xt, const void* h0g, const void* wihg,
                      const void* whhg, const void* bihg, const void* bhhg,
                      float* __restrict__ Wout, const int* flagp) {
  __shared__ float wb1[64 * GS];   // wih^T  [f][o], 49.4KB
  __shared__ float wb2[64 * GS];   // whh^T  [f][o], 49.4KB
  __shared__ float xtr[256];
  __shared__ float h0r[256];
  int flag = flagp[0];
  int t = threadIdx.x;
  int j0 = blockIdx.x * 4;
  { int jj = t >> 6, f = t & 63;
    xtr[t] = xt[(j0 + jj) * 64 + f];
    h0r[t] = ldf(h0g, (j0 + jj) * 64 + f, flag); }
  stage_w(wihg, wb1, flag, t);
  stage_w(whhg, wb2, flag, t);
  __syncthreads();
  int jl = t >> 6, c2 = t & 63;
  float xr = 0, xz = 0, xn = 0, hr = 0, hz = 0, hn = 0;
#pragma unroll 4
  for (int f = 0; f < 64; f++) {
    float xv = xtr[jl * 64 + f];
    float hv = h0r[jl * 64 + f];
    const float* w1 = &wb1[f * GS];
    const float* w2 = &wb2[f * GS];
    xr += xv * w1[c2]; xz += xv * w1[64 + c2]; xn += xv * w1[128 + c2];
    hr += hv * w2[c2]; hz += hv * w2[64 + c2]; hn += hv * w2[128 + c2];
  }
  xr += ldf(bihg, c2, flag); xz += ldf(bihg, 64 + c2, flag); xn += ldf(bihg, 128 + c2, flag);
  hr += ldf(bhhg, c2, flag); hz += ldf(bhhg, 64 + c2, flag); hn += ldf(bhhg, 128 + c2, flag);
  float rg = 1.f / (1.f + expf(-(xr + hr)));
  float zg = 1.f / (1.f + expf(-(xz + hz)));
  float nc = tanhf(xn + rg * hn);
  Wout[(j0 + jl) * 64 + c2] = (1.f - zg) * nc + zg * h0r[jl * 64 + c2];
}

// ---- tail stage 1: g[o] = pooled @ gnn_fc_w.T + gnn_fc_b  (64 blocks) ----
__global__ void k_g(const float* __restrict__ svec, const float* __restrict__ Wm,
                    const void* gw, const void* gb, float* __restrict__ g,
                    const int* flagp) {
  __shared__ float pooled[64];
  int flag = flagp[0];
  int t = threadIdx.x, w = t >> 6, lane = t & 63;
  if (t < 64) {
    float a = 0.f;
    for (int f = 0; f < 64; f++) a += svec[f] * Wm[f * 64 + t];
    pooled[t] = a * (1.0f / (float)NN);
  }
  __syncthreads();
  int o = blockIdx.x * 4 + w;      // 0..255
  float acc = pooled[lane] * ldf(gw, o * 64 + lane, flag);
  acc = wsum(acc);
  if (lane == 0) g[o] = acc + ldf(gb, o, flag);
}

// ---- tail stage 2: layernorm over [g | d] -> lnv (1 block, tiny traffic) ----
__global__ void k_ln(const float* __restrict__ g, const float* __restrict__ d,
                     const void* lng, const void* lnb, float* __restrict__ lnv,
                     const int* flagp) {
  __shared__ float red[256];
  __shared__ float stats[2];
  int flag = flagp[0];
  int t = threadIdx.x;
  float v0 = g[t], v1 = d[t];
  red[t] = v0 + v1; __syncthreads();
  for (int s = 128; s > 0; s >>= 1) { if (t < s) red[t] += red[t + s]; __syncthreads(); }
  if (t == 0) stats[0] = red[0];
  __syncthreads();
  red[t] = v0 * v0 + v1 * v1; __syncthreads();
  for (int s = 128; s > 0; s >>= 1) { if (t < s) red[t] += red[t + s]; __syncthreads(); }
  if (t == 0) stats[1] = red[0];
  __syncthreads();
  float mu = stats[0] * (1.f / 512.f);
  float var = stats[1] * (1.f / 512.f) - mu * mu;
  float istd = rsqrtf(var + 1e-5f);
  lnv[t]       = (v0 - mu) * istd * ldf(lng, t, flag)       + ldf(lnb, t, flag);
  lnv[t + 256] = (v1 - mu) * istd * ldf(lng, t + 256, flag) + ldf(lnb, t + 256, flag);
}

// ---- tail stage 3: h1 = relu(lnv @ fusion_w.T + fb) (64 blocks, uint4 row loads) ----
__global__ void k_fuse(const float* __restrict__ lnv, const void* fw, const void* fb,
                       float* __restrict__ h1, const int* flagp) {
  __shared__ float lv[512];
  int flag = flagp[0];
  int t = threadIdx.x, w = t >> 6, lane = t & 63;
  lv[t] = lnv[t]; lv[t + 256] = lnv[t + 256];
  __syncthreads();
  int o = blockIdx.x * 4 + w;      // 0..255
  float acc = 0.f;
  if (flag) {
    uint4 u = *((const uint4*)((const unsigned short*)fw + o * 512) + lane);  // 8 bf16
    const float* l = &lv[lane * 8];
    acc = bfu(u.x & 0xffff) * l[0] + bfu(u.x >> 16) * l[1]
        + bfu(u.y & 0xffff) * l[2] + bfu(u.y >> 16) * l[3]
        + bfu(u.z & 0xffff) * l[4] + bfu(u.z >> 16) * l[5]
        + bfu(u.w & 0xffff) * l[6] + bfu(u.w >> 16) * l[7];
  } else {
    const float4* fv = (const float4*)((const float*)fw + o * 512);
    float4 a = fv[lane * 2], b = fv[lane * 2 + 1];
    const float* l = &lv[lane * 8];
    acc = a.x * l[0] + a.y * l[1] + a.z * l[2] + a.w * l[3]
        + b.x * l[4] + b.y * l[5] + b.z * l[6] + b.w * l[7];
  }
  acc = wsum(acc);
  if (lane == 0) h1[o] = fmaxf(acc + ldf(fb, o, flag), 0.0f);
}

// ---- tail stage 4: task + time heads (5 blocks) ----
__global__ void k_out(const float* __restrict__ h1, const void* tw, const void* tb,
                      const void* tmw, const void* tmb, void* out, const int* flagp) {
  int flag = flagp[0];
  int t = threadIdx.x, w = t >> 6, lane = t & 63;
  int o = blockIdx.x * 4 + w;
  if (o >= 17) return;
  float acc = 0.f;
  if (o < 16) { for (int k = lane; k < 256; k += 64) acc += h1[k] * ldf(tw, o * 256 + k, flag); }
  else        { for (int k = lane; k < 256; k += 64) acc += h1[k] * ldf(tmw, k, flag); }
  acc = wsum(acc);
  if (lane == 0) {
    float bias = (o < 16) ? ldf(tb, o, flag) : ldf(tmb, 0, flag);
    stf(out, o, acc + bias, flag);
  }
}

extern "C" void kernel_launch(void* const* d_in, const int* in_sizes, int n_in,
                              void* d_out, int out_size, void* d_ws, size_t ws_size,
                              hipStream_t stream) {
  const void* x    = d_in[0];
  const int*  ei   = (const int*)d_in[1];
  const void* docf = d_in[2];
  const void* pw   = d_in[3];
  const void* h0   = d_in[4];
  const void* wih  = d_in[5];
  const void* whh  = d_in[6];
  const void* bih  = d_in[7];
  const void* bhh  = d_in[8];
  const void* gw   = d_in[9];
  const void* gb   = d_in[10];
  const void* dw   = d_in[11];
  const void* db   = d_in[12];
  const void* lng  = d_in[13];
  const void* lnb  = d_in[14];
  const void* fw   = d_in[15];
  const void* fb   = d_in[16];
  const void* tw   = d_in[17];
  const void* tb   = d_in[18];
  const void* tmw  = d_in[19];
  const void* tmb  = d_in[20];

  const int* row = ei;
  const int* col = ei + EE;

  float* wsf = (float*)d_ws;
  int*   wsi = (int*)d_ws;

  hipMemsetAsync(wsi + P_DEGM, 0, (size_t)ZLEN1 * 4, stream);       // degm8
  hipMemsetAsync(wsi + P_CANDN, 0, (size_t)ZERO_LEN * 4, stream);
  k_detect<<<1, 256, 0, stream>>>((const unsigned short*)x, wsi + P_FLAG);
  k_hcol<<<NBC * CCC, HTH, 0, stream>>>(col, (unsigned*)(wsi + P_DEGM));
  k_redA<<<NDBLK + 64, 256, 0, stream>>>((const unsigned*)(wsi + P_DEGM), wsf + P_DIS,
                                         docf, dw, db, wsf + P_D, wsi + P_FLAG);
  hipMemsetAsync(wsi + P_PARTM, 0, (size_t)ZLEN2 * 4, stream);      // partm8 (degm dead)
  k_hrow<<<NBR * CCR, HTH, 0, stream>>>(row, col, wsf + P_DIS, wsf + P_PARTM);
  k_redB<<<NDBLK, 256, 0, stream>>>(wsf + P_PARTM, wsf + P_DIS, wsf + P_C);
  k_x<<<XBLOCKS, 256, 0, stream>>>(x, pw, wsf + P_C, wsf + P_SCORE,
                                   wsf + P_S8, wsi + P_FLAG);
  k_hist<<<HB, 1024, 0, stream>>>(wsf + P_SCORE, (unsigned*)(wsi + P_PART));
  k_redH<<<HW / 256, 256, 0, stream>>>((const unsigned*)(wsi + P_PART), wsi + P_HIST);
  k_thresh<<<1, 256, 0, stream>>>(wsi + P_HIST, wsi + P_THR, wsf + P_S8, wsf + P_SV);
  k_collect<<<NDBLK, 256, 0, stream>>>(wsf + P_SCORE, wsi + P_THR, wsi + P_CANDN,
                                       (unsigned*)(wsi + P_CKEY), wsi + P_CIDX);
  k_top<<<1, 1024, 0, stream>>>(wsi + P_CANDN, (const unsigned*)(wsi + P_CKEY),
                                wsi + P_CIDX, x, wsf + P_XT, wsi + P_FLAG);
  k_gru<<<16, 256, 0, stream>>>(wsf + P_XT, h0, wih, whh, bih, bhh, wsf + P_WW, wsi + P_FLAG);
  k_g<<<64, 256, 0, stream>>>(wsf + P_SV, wsf + P_WW, gw, gb, wsf + P_G, wsi + P_FLAG);
  k_ln<<<1, 256, 0, stream>>>(wsf + P_G, wsf + P_D, lng, lnb, wsf + P_LNV, wsi + P_FLAG);
  k_fuse<<<64, 256, 0, stream>>>(wsf + P_LNV, fw, fb, wsf + P_H1, wsi + P_FLAG);
  k_out<<<5, 256, 0, stream>>>(wsf + P_H1, tw, tb, tmw, tmb, d_out, wsi + P_FLAG);
}

// Round 8
// 308.298 us; speedup vs baseline: 1.0552x; 1.0552x over previous
//
#include <hip/hip_runtime.h>
#include <hip/hip_bf16.h>

#define NN    200000
#define EE    3200000
#define DDIMC 768

#define NI4   800000    // EE/4 int4s
#define HTH   1024      // histogram block threads
#define PARTW (25 * 12 * 8192)   // legacy region size (fallback layout)

// hcol: packed 2x16-bit counts, 32768 nodes / 64KB LDS, 7 passes
// CC multiple of 8: same-j blocks share one XCD's L2 for the edge re-read.
#define BSZC  32768
#define BSHC  15
#define NBC   7
#define CCC   72        // 7*72 = 504 blocks
#define DEGC  (NBC * (BSZC / 2))     // per-copy words (fallback 8-copy path)
// hrow: float, 16384 nodes / 64KB LDS, 13 passes
#define BSZR  16384
#define BSHR  14
#define NBR   13
#define CCR   40        // 13*40 = 520 blocks
#define PARTC (NBR * BSZR)

#define NDBLK 782       // ceil(NN/256)
#define XBLOCKS 1024
#define CAPL  4096

#define HB    64        // score-hist partial blocks (NN/HB = 3125 exact)
#define HW    32768     // packed u32 words (2x16-bit counts) = 65536 buckets

// Fallback (small-ws) layout constants
#define ZLEN1   (8 * DEGC)
#define ZLEN2   (8 * PARTC)
// Big-path partial region: 520 blocks x 16384 words (hcol's 504x16384 fits too)
#define BIGPART (CCR * NBR * BSZR)   // 8519680 words

// ---- helpers (proven) ----
__device__ __forceinline__ float ldf(const void* p, int i, int bf) {
  if (bf) return __bfloat162float(((const __hip_bfloat16*)p)[i]);
  return ((const float*)p)[i];
}
__device__ __forceinline__ void stf(void* p, int i, float v, int bf) {
  if (bf) ((__hip_bfloat16*)p)[i] = __float2bfloat16(v);
  else ((float*)p)[i] = v;
}
__device__ __forceinline__ float bfu(unsigned u) {   // low 16 bits -> bf16 value
  return __uint_as_float(u << 16);
}
__device__ __forceinline__ float wsum(float v) {
#pragma unroll
  for (int m = 32; m >= 1; m >>= 1) v += __shfl_xor(v, m, 64);
  return v;
}
__device__ __forceinline__ int wsumi(int v) {
#pragma unroll
  for (int m = 32; m >= 1; m >>= 1) v += __shfl_xor(v, m, 64);
  return v;
}
__device__ __forceinline__ unsigned sortkey(float f) {
  unsigned u = __float_as_uint(f);
  return (u & 0x80000000u) ? ~u : (u | 0x80000000u);
}

// ---- dtype detector (proven) ----
__global__ void k_detect(const unsigned short* x16, int* flag) {
  __shared__ int cnt;
  if (threadIdx.x == 0) cnt = 0;
  __syncthreads();
  int ok = 0;
  for (int k = threadIdx.x; k < 512; k += 256) {
    unsigned short u = x16[2 * k];
    int e = (u >> 7) & 0xFF;
    if (u == 0 || (e >= 100 && e <= 150)) ok++;
  }
  atomicAdd(&cnt, ok);
  __syncthreads();
  if (threadIdx.x == 0) flag[0] = (cnt >= 400) ? 1 : 0;
}

// ================= BIG-WS PATH: plain per-block stores, no global atomics ====
// R7 evidence: WRITE_SIZE == 4B x atomic-count, invariant under XCD-locality
// -> global atomics are memory-side RMWs. Store each block's private LDS
// histogram (coalesced streaming), reduce the copies in redA/redB.

__global__ void __launch_bounds__(HTH) k_hcolB(const int* __restrict__ col,
                                               unsigned* __restrict__ part) {
  __shared__ unsigned lh[BSZC / 2];
  int t = threadIdx.x;
  int b = blockIdx.x / CCC, j = blockIdx.x % CCC;
  for (int k = t; k < BSZC / 2; k += HTH) lh[k] = 0u;
  __syncthreads();
  int base = b << BSHC;
  const int4* c4 = (const int4*)col;
  const int stride = CCC * HTH;
  for (int i = j * HTH + t; i < NI4; i += 2 * stride) {
    int4 v0 = c4[i];
    int i2 = i + stride;
    int4 v1; v1.x = v1.y = v1.z = v1.w = -1;
    if (i2 < NI4) v1 = c4[i2];
    {
      int a0 = v0.x - base, a1 = v0.y - base, a2 = v0.z - base, a3 = v0.w - base;
      if ((unsigned)a0 < (unsigned)BSZC) atomicAdd(&lh[a0 >> 1], 1u << ((a0 & 1) * 16));
      if ((unsigned)a1 < (unsigned)BSZC) atomicAdd(&lh[a1 >> 1], 1u << ((a1 & 1) * 16));
      if ((unsigned)a2 < (unsigned)BSZC) atomicAdd(&lh[a2 >> 1], 1u << ((a2 & 1) * 16));
      if ((unsigned)a3 < (unsigned)BSZC) atomicAdd(&lh[a3 >> 1], 1u << ((a3 & 1) * 16));
    }
    {
      int a0 = v1.x - base, a1 = v1.y - base, a2 = v1.z - base, a3 = v1.w - base;
      if ((unsigned)a0 < (unsigned)BSZC) atomicAdd(&lh[a0 >> 1], 1u << ((a0 & 1) * 16));
      if ((unsigned)a1 < (unsigned)BSZC) atomicAdd(&lh[a1 >> 1], 1u << ((a1 & 1) * 16));
      if ((unsigned)a2 < (unsigned)BSZC) atomicAdd(&lh[a2 >> 1], 1u << ((a2 & 1) * 16));
      if ((unsigned)a3 < (unsigned)BSZC) atomicAdd(&lh[a3 >> 1], 1u << ((a3 & 1) * 16));
    }
  }
  __syncthreads();
  unsigned* dst = part + (size_t)blockIdx.x * (BSZC / 2);
  for (int k = 4 * t; k < BSZC / 2; k += 4 * HTH)
    *(uint4*)&dst[k] = *(const uint4*)&lh[k];
}

__global__ void k_redAB(const unsigned* __restrict__ part, float* __restrict__ dis,
                        const void* docf, const void* dw, const void* db,
                        float* __restrict__ d, const int* flagp) {
  if (blockIdx.x < NDBLK) {
    int i = blockIdx.x * 256 + threadIdx.x;
    if (i < NN) {
      int b = i >> BSHC;
      int k = (i & (BSZC - 1)) >> 1;
      const unsigned* p = part + (size_t)b * CCC * (BSZC / 2) + k;
      unsigned s = 0;
#pragma unroll 8
      for (int j = 0; j < CCC; j++) s += p[(size_t)j * (BSZC / 2)];
      // packed 2x16 fields: per-node totals << 2^16, no cross-field carry
      int deg = 1 + (int)((s >> ((i & 1) * 16)) & 0xffffu);
      dis[i] = rsqrtf((float)deg);
    }
  } else {
    int flag = flagp[0];
    int o = (blockIdx.x - NDBLK) * 4 + (threadIdx.x >> 6);
    int lane = threadIdx.x & 63;
    float acc = 0.f;
    for (int k = lane; k < DDIMC; k += 64) acc += ldf(docf, k, flag) * ldf(dw, o * DDIMC + k, flag);
    acc = wsum(acc);
    if (lane == 0) d[o] = fmaxf(acc + ldf(db, o, flag), 0.0f);
  }
}

__global__ void __launch_bounds__(HTH) k_hrowB(const int* __restrict__ row, const int* __restrict__ col,
                                               const float* __restrict__ dis,
                                               float* __restrict__ part) {
  __shared__ float lh[BSZR];
  int t = threadIdx.x;
  int b = blockIdx.x / CCR, j = blockIdx.x % CCR;
  for (int k = t; k < BSZR; k += HTH) lh[k] = 0.f;
  __syncthreads();
  int base = b << BSHR;
  const int4* r4 = (const int4*)row;
  const int4* c4 = (const int4*)col;
  const int stride = CCR * HTH;
  for (int i = j * HTH + t; i < NI4; i += 2 * stride) {
    int4 r0 = r4[i];
    int4 c0 = c4[i];
    int i2 = i + stride;
    int4 r1; r1.x = r1.y = r1.z = r1.w = -1;
    int4 c1; c1.x = c1.y = c1.z = c1.w = 0;
    if (i2 < NI4) { r1 = r4[i2]; c1 = c4[i2]; }
    {
      int a0 = r0.x - base, a1 = r0.y - base, a2 = r0.z - base, a3 = r0.w - base;
      if ((unsigned)a0 < (unsigned)BSZR) atomicAdd(&lh[a0], dis[c0.x]);
      if ((unsigned)a1 < (unsigned)BSZR) atomicAdd(&lh[a1], dis[c0.y]);
      if ((unsigned)a2 < (unsigned)BSZR) atomicAdd(&lh[a2], dis[c0.z]);
      if ((unsigned)a3 < (unsigned)BSZR) atomicAdd(&lh[a3], dis[c0.w]);
    }
    {
      int a0 = r1.x - base, a1 = r1.y - base, a2 = r1.z - base, a3 = r1.w - base;
      if ((unsigned)a0 < (unsigned)BSZR) atomicAdd(&lh[a0], dis[c1.x]);
      if ((unsigned)a1 < (unsigned)BSZR) atomicAdd(&lh[a1], dis[c1.y]);
      if ((unsigned)a2 < (unsigned)BSZR) atomicAdd(&lh[a2], dis[c1.z]);
      if ((unsigned)a3 < (unsigned)BSZR) atomicAdd(&lh[a3], dis[c1.w]);
    }
  }
  __syncthreads();
  float* dst = part + (size_t)blockIdx.x * BSZR;
  for (int k = 4 * t; k < BSZR; k += 4 * HTH)
    *(float4*)&dst[k] = *(const float4*)&lh[k];
}

__global__ void k_redBB(const float* __restrict__ part, const float* __restrict__ dis,
                        float* __restrict__ c) {
  int i = blockIdx.x * 256 + threadIdx.x;
  if (i < NN) {
    int b = i >> BSHR;
    int k = i & (BSZR - 1);
    const float* p = part + (size_t)b * CCR * BSZR + k;
    float s = 0.f;
#pragma unroll 8
    for (int j = 0; j < CCR; j++) s += p[(size_t)j * BSZR];
    float dv = dis[i];
    c[i] = dv * s + dv * dv;
  }
}

// ================= FALLBACK PATH (R7 code, proven): atomic 8-copy merge =====
__global__ void __launch_bounds__(HTH) k_hcol(const int* __restrict__ col,
                                              unsigned* __restrict__ degm) {
  __shared__ unsigned lh[BSZC / 2];
  int t = threadIdx.x;
  int b = blockIdx.x / CCC, j = blockIdx.x % CCC;
  for (int k = t; k < BSZC / 2; k += HTH) lh[k] = 0u;
  __syncthreads();
  int base = b << BSHC;
  const int4* c4 = (const int4*)col;
  const int stride = CCC * HTH;
  for (int i = j * HTH + t; i < NI4; i += 2 * stride) {
    int4 v0 = c4[i];
    int i2 = i + stride;
    int4 v1; v1.x = v1.y = v1.z = v1.w = -1;
    if (i2 < NI4) v1 = c4[i2];
    {
      int a0 = v0.x - base, a1 = v0.y - base, a2 = v0.z - base, a3 = v0.w - base;
      if ((unsigned)a0 < (unsigned)BSZC) atomicAdd(&lh[a0 >> 1], 1u << ((a0 & 1) * 16));
      if ((unsigned)a1 < (unsigned)BSZC) atomicAdd(&lh[a1 >> 1], 1u << ((a1 & 1) * 16));
      if ((unsigned)a2 < (unsigned)BSZC) atomicAdd(&lh[a2 >> 1], 1u << ((a2 & 1) * 16));
      if ((unsigned)a3 < (unsigned)BSZC) atomicAdd(&lh[a3 >> 1], 1u << ((a3 & 1) * 16));
    }
    {
      int a0 = v1.x - base, a1 = v1.y - base, a2 = v1.z - base, a3 = v1.w - base;
      if ((unsigned)a0 < (unsigned)BSZC) atomicAdd(&lh[a0 >> 1], 1u << ((a0 & 1) * 16));
      if ((unsigned)a1 < (unsigned)BSZC) atomicAdd(&lh[a1 >> 1], 1u << ((a1 & 1) * 16));
      if ((unsigned)a2 < (unsigned)BSZC) atomicAdd(&lh[a2 >> 1], 1u << ((a2 & 1) * 16));
      if ((unsigned)a3 < (unsigned)BSZC) atomicAdd(&lh[a3 >> 1], 1u << ((a3 & 1) * 16));
    }
  }
  __syncthreads();
  unsigned* dst = degm + (size_t)(j & 7) * DEGC + (size_t)b * (BSZC / 2);
  for (int k = t; k < BSZC / 2; k += HTH) {
    unsigned v = lh[k];
    if (v) atomicAdd(&dst[k], v);
  }
}

__global__ void k_redA(const unsigned* __restrict__ degm, float* __restrict__ dis,
                       const void* docf, const void* dw, const void* db,
                       float* __restrict__ d, const int* flagp) {
  if (blockIdx.x < NDBLK) {
    int i = blockIdx.x * 256 + threadIdx.x;
    if (i < NN) {
      int sh = (i & 1) * 16;
      int deg = 1;
#pragma unroll
      for (int p = 0; p < 8; p++) {
        unsigned w_ = degm[(size_t)p * DEGC + (i >> 1)];
        deg += (int)((w_ >> sh) & 0xffffu);
      }
      dis[i] = rsqrtf((float)deg);
    }
  } else {
    int flag = flagp[0];
    int o = (blockIdx.x - NDBLK) * 4 + (threadIdx.x >> 6);
    int lane = threadIdx.x & 63;
    float acc = 0.f;
    for (int k = lane; k < DDIMC; k += 64) acc += ldf(docf, k, flag) * ldf(dw, o * DDIMC + k, flag);
    acc = wsum(acc);
    if (lane == 0) d[o] = fmaxf(acc + ldf(db, o, flag), 0.0f);
  }
}

__global__ void __launch_bounds__(HTH) k_hrow(const int* __restrict__ row, const int* __restrict__ col,
                                              const float* __restrict__ dis,
                                              float* __restrict__ partm) {
  __shared__ float lh[BSZR];
  int t = threadIdx.x;
  int b = blockIdx.x / CCR, j = blockIdx.x % CCR;
  for (int k = t; k < BSZR; k += HTH) lh[k] = 0.f;
  __syncthreads();
  int base = b << BSHR;
  const int4* r4 = (const int4*)row;
  const int4* c4 = (const int4*)col;
  const int stride = CCR * HTH;
  for (int i = j * HTH + t; i < NI4; i += 2 * stride) {
    int4 r0 = r4[i];
    int4 c0 = c4[i];
    int i2 = i + stride;
    int4 r1; r1.x = r1.y = r1.z = r1.w = -1;
    int4 c1; c1.x = c1.y = c1.z = c1.w = 0;
    if (i2 < NI4) { r1 = r4[i2]; c1 = c4[i2]; }
    {
      int a0 = r0.x - base, a1 = r0.y - base, a2 = r0.z - base, a3 = r0.w - base;
      if ((unsigned)a0 < (unsigned)BSZR) atomicAdd(&lh[a0], dis[c0.x]);
      if ((unsigned)a1 < (unsigned)BSZR) atomicAdd(&lh[a1], dis[c0.y]);
      if ((unsigned)a2 < (unsigned)BSZR) atomicAdd(&lh[a2], dis[c0.z]);
      if ((unsigned)a3 < (unsigned)BSZR) atomicAdd(&lh[a3], dis[c0.w]);
    }
    {
      int a0 = r1.x - base, a1 = r1.y - base, a2 = r1.z - base, a3 = r1.w - base;
      if ((unsigned)a0 < (unsigned)BSZR) atomicAdd(&lh[a0], dis[c1.x]);
      if ((unsigned)a1 < (unsigned)BSZR) atomicAdd(&lh[a1], dis[c1.y]);
      if ((unsigned)a2 < (unsigned)BSZR) atomicAdd(&lh[a2], dis[c1.z]);
      if ((unsigned)a3 < (unsigned)BSZR) atomicAdd(&lh[a3], dis[c1.w]);
    }
  }
  __syncthreads();
  float* dst = partm + (size_t)(j & 7) * PARTC + (size_t)b * BSZR;
  for (int k = t; k < BSZR; k += HTH) {
    float v = lh[k];
    if (v != 0.f) atomicAdd(&dst[k], v);
  }
}

__global__ void k_redB(const float* __restrict__ partm, const float* __restrict__ dis,
                       float* __restrict__ c) {
  int i = blockIdx.x * 256 + threadIdx.x;
  if (i < NN) {
    float s = 0.f;
#pragma unroll
    for (int p = 0; p < 8; p++) s += partm[(size_t)p * PARTC + i];
    float dv = dis[i];
    c[i] = dv * s + dv * dv;
  }
}

// ---- fused x pass (proven R2): pure stream, score + column accumulator ----
__global__ void k_x(const void* x, const void* pw, const float* __restrict__ c,
                    float* __restrict__ score,
                    float* __restrict__ s8, const int* flagp) {
  __shared__ float sred[4][64];
  int flag = flagp[0];
  int t = threadIdx.x;
  int lane = t & 63;
  int w = t >> 6;
  int wid = (blockIdx.x * 256 + t) >> 6;
  int nw = (gridDim.x * 256) >> 6;

  if (flag) {
    int g  = lane >> 3;
    int c0 = (lane & 7) * 8;
    float pwv[8];
#pragma unroll
    for (int j = 0; j < 8; j++) pwv[j] = ldf(pw, c0 + j, 1);
    float s = 0.f;
#pragma unroll
    for (int j = 0; j < 8; j++) s += pwv[j] * pwv[j];
    float inv = 1.0f / sqrtf(wsum(s) * 0.125f);
    float sacc[8] = {0.f, 0.f, 0.f, 0.f, 0.f, 0.f, 0.f, 0.f};
    const uint4* x4 = (const uint4*)x;
    for (int r0 = wid * 8; r0 < NN; r0 += nw * 8) {
      int r = r0 + g;
      uint4 u = x4[r * 8 + (lane & 7)];
      float xv[8] = { bfu(u.x & 0xffff), bfu(u.x >> 16),
                      bfu(u.y & 0xffff), bfu(u.y >> 16),
                      bfu(u.z & 0xffff), bfu(u.z >> 16),
                      bfu(u.w & 0xffff), bfu(u.w >> 16) };
      float dot = 0.f;
#pragma unroll
      for (int j = 0; j < 8; j++) dot += xv[j] * pwv[j];
      dot += __shfl_xor(dot, 1, 64);
      dot += __shfl_xor(dot, 2, 64);
      dot += __shfl_xor(dot, 4, 64);
      float cr = c[r];
#pragma unroll
      for (int j = 0; j < 8; j++) sacc[j] += cr * xv[j];
      if ((lane & 7) == 0) score[r] = dot * inv;
    }
#pragma unroll
    for (int j = 0; j < 8; j++) {
      sacc[j] += __shfl_xor(sacc[j], 8, 64);
      sacc[j] += __shfl_xor(sacc[j], 16, 64);
      sacc[j] += __shfl_xor(sacc[j], 32, 64);
    }
    if (lane < 8) {
#pragma unroll
      for (int j = 0; j < 8; j++) sred[w][lane * 8 + j] = sacc[j];
    }
  } else {
    int g  = lane >> 4;
    int c0 = (lane & 15) * 4;
    float pwv[4];
#pragma unroll
    for (int j = 0; j < 4; j++) pwv[j] = ((const float*)pw)[c0 + j];
    float s = 0.f;
#pragma unroll
    for (int j = 0; j < 4; j++) s += pwv[j] * pwv[j];
    float inv = 1.0f / sqrtf(wsum(s) * (1.f / 16.f));
    float sacc[4] = {0.f, 0.f, 0.f, 0.f};
    const float4* x4 = (const float4*)x;
    for (int r0 = wid * 4; r0 < NN; r0 += nw * 4) {
      int r = r0 + g;
      float4 v = x4[r * 16 + (lane & 15)];
      float xv[4] = { v.x, v.y, v.z, v.w };
      float dot = 0.f;
#pragma unroll
      for (int j = 0; j < 4; j++) dot += xv[j] * pwv[j];
      dot += __shfl_xor(dot, 1, 64);
      dot += __shfl_xor(dot, 2, 64);
      dot += __shfl_xor(dot, 4, 64);
      dot += __shfl_xor(dot, 8, 64);
      float cr = c[r];
#pragma unroll
      for (int j = 0; j < 4; j++) sacc[j] += cr * xv[j];
      if ((lane & 15) == 0) score[r] = dot * inv;
    }
#pragma unroll
    for (int j = 0; j < 4; j++) {
      sacc[j] += __shfl_xor(sacc[j], 16, 64);
      sacc[j] += __shfl_xor(sacc[j], 32, 64);
    }
    if (lane < 16) {
#pragma unroll
      for (int j = 0; j < 4; j++) sred[w][lane * 4 + j] = sacc[j];
    }
  }
  __syncthreads();
  if (w == 0)
    atomicAdd(&s8[(blockIdx.x & 7) * 64 + lane],
              sred[0][lane] + sred[1][lane] + sred[2][lane] + sred[3][lane]);
}

// ---- LDS-privatized full-resolution score histogram (proven R2) ----
__global__ void __launch_bounds__(1024) k_hist(const float* __restrict__ score,
                                               unsigned* __restrict__ part) {
  __shared__ unsigned lh[HW];
  int t = threadIdx.x;
  for (int k = t; k < HW; k += 1024) lh[k] = 0u;
  __syncthreads();
  int r0 = blockIdx.x * (NN / HB);
  int r1 = r0 + (NN / HB);
  for (int i = r0 + t; i < r1; i += 1024) {
    unsigned b = sortkey(score[i]) >> 16;
    atomicAdd(&lh[b >> 1], 1u << ((b & 1) * 16));
  }
  __syncthreads();
  unsigned* dst = part + (size_t)blockIdx.x * HW;
  for (int k = t; k < HW; k += 1024) dst[k] = lh[k];
}

// ---- sum HB packed partials -> hist (proven R2) ----
__global__ void k_redH(const unsigned* __restrict__ part, int* __restrict__ hist) {
  int w = blockIdx.x * 256 + threadIdx.x;
  unsigned lo = 0, hi = 0;
  for (int b = 0; b < HB; b++) {
    unsigned v = part[(size_t)b * HW + w];
    lo += v & 0xffffu;
    hi += v >> 16;
  }
  hist[2 * w]     = (int)lo;
  hist[2 * w + 1] = (int)hi;
}

// ---- threshold (proven) ----
__global__ void k_thresh(const int* __restrict__ hist, int* __restrict__ thrB,
                         const float* __restrict__ s8, float* __restrict__ svec) {
  __shared__ int part[256];
  __shared__ int segl[256];
  __shared__ int res2[2];
  int t = threadIdx.x, w = t >> 6, lane = t & 63;
  if (t < 64) {
    float a = 0.f;
    for (int r = 0; r < 8; r++) a += s8[r * 64 + t];
    svec[t] = a;
  }
  for (int m = w; m < 256; m += 4) {
    const int* hb = &hist[m * 256];
    int a = hb[lane] + hb[lane + 64] + hb[lane + 128] + hb[lane + 192];
    a = wsumi(a);
    if (lane == 0) part[m] = a;
  }
  __syncthreads();
  if (t == 0) {
    int acc = 0, seg = 0, above = 0;
    for (int b = 255; b >= 0; b--) {
      if (acc + part[b] >= 64) { seg = b; above = acc; break; }
      acc += part[b];
    }
    res2[0] = seg; res2[1] = above;
  }
  __syncthreads();
  segl[t] = hist[res2[0] * 256 + t];
  __syncthreads();
  if (t == 0) {
    int acc = res2[1], B = res2[0] * 256;
    for (int j = 255; j >= 0; j--) {
      acc += segl[j];
      if (acc >= 64) { B = res2[0] * 256 + j; break; }
    }
    thrB[0] = B;
  }
}

// ---- collect (proven) ----
__global__ void k_collect(const float* __restrict__ score, const int* __restrict__ thrB,
                          int* __restrict__ candn, unsigned* __restrict__ ckey,
                          int* __restrict__ cidx) {
  int i = blockIdx.x * blockDim.x + threadIdx.x;
  if (i >= NN) return;
  unsigned u = sortkey(score[i]);
  if ((int)(u >> 16) >= thrB[0]) {
    int p = atomicAdd(candn, 1);
    if (p < CAPL) { ckey[p] = u; cidx[p] = i; }
  }
}

// ---- top-64 (1024 threads) ----
__global__ void __launch_bounds__(1024) k_top(const int* __restrict__ candn,
                      const unsigned* __restrict__ ckey,
                      const int* __restrict__ cidx, const void* x,
                      float* __restrict__ xt, const int* flagp) {
  __shared__ unsigned long long keys[CAPL];
  __shared__ int perm[64];
  __shared__ float ts[64];
  int flag = flagp[0];
  int t = threadIdx.x;
  int M = candn[0];
  if (M > CAPL) M = CAPL;
  for (int j = t; j < M; j += 1024)
    keys[j] = (((unsigned long long)ckey[j]) << 32) |
              (unsigned long long)(0xFFFFFFFFu - (unsigned)cidx[j]);
  __syncthreads();
  for (int j = t; j < M; j += 1024) {
    unsigned long long k = keys[j];
    int rank = 0;
    for (int i = 0; i < M; i++) rank += (keys[i] > k) ? 1 : 0;
    if (rank < 64) {
      unsigned ku = (unsigned)(k >> 32);
      unsigned idx = 0xFFFFFFFFu - (unsigned)(k & 0xFFFFFFFFu);
      perm[rank] = (int)idx;
      unsigned bits = (ku & 0x80000000u) ? (ku ^ 0x80000000u) : ~ku;
      ts[rank] = tanhf(__uint_as_float(bits));
    }
  }
  __syncthreads();
  for (int q = t; q < 4096; q += 1024) {
    int j = q >> 6, f = q & 63;
    xt[q] = ldf(x, perm[j] * 64 + f, flag) * ts[j];
  }
}

// ---- GRU (proven round-0 rework): coalesced staging, LDS-side transpose ----
#define GS 193
__device__ __forceinline__ void stage_w(const void* src, float* dst, int flag, int t) {
  if (flag) {
    const uint4* s4 = (const uint4*)src;
    for (int k = t; k < 1536; k += 256) {
      uint4 u = s4[k];
      int e = k << 3; int o = e >> 6, f = e & 63;
      float* d = &dst[f * GS + o];
      d[0]      = bfu(u.x & 0xffff); d[GS]     = bfu(u.x >> 16);
      d[2 * GS] = bfu(u.y & 0xffff); d[3 * GS] = bfu(u.y >> 16);
      d[4 * GS] = bfu(u.z & 0xffff); d[5 * GS] = bfu(u.z >> 16);
      d[6 * GS] = bfu(u.w & 0xffff); d[7 * GS] = bfu(u.w >> 16);
    }
  } else {
    const float4* s4 = (const float4*)src;
    for (int k = t; k < 3072; k += 256) {
      float4 v = s4[k];
      int e = k << 2; int o = e >> 6, f = e & 63;
      float* d = &dst[f * GS + o];
      d[0] = v.x; d[GS] = v.y; d[2 * GS] = v.z; d[3 * GS] = v.w;
    }
  }
}

__global__ void k_gru(const float* __restrict__ xt, const void* h0g, const void* wihg,
                      const void* whhg, const void* bihg, const void* bhhg,
                      float* __restrict__ Wout, const int* flagp) {
  __shared__ float wb1[64 * GS];
  __shared__ float wb2[64 * GS];
  __shared__ float xtr[256];
  __shared__ float h0r[256];
  int flag = flagp[0];
  int t = threadIdx.x;
  int j0 = blockIdx.x * 4;
  { int jj = t >> 6, f = t & 63;
    xtr[t] = xt[(j0 + jj) * 64 + f];
    h0r[t] = ldf(h0g, (j0 + jj) * 64 + f, flag); }
  stage_w(wihg, wb1, flag, t);
  stage_w(whhg, wb2, flag, t);
  __syncthreads();
  int jl = t >> 6, c2 = t & 63;
  float xr = 0, xz = 0, xn = 0, hr = 0, hz = 0, hn = 0;
#pragma unroll 4
  for (int f = 0; f < 64; f++) {
    float xv = xtr[jl * 64 + f];
    float hv = h0r[jl * 64 + f];
    const float* w1 = &wb1[f * GS];
    const float* w2 = &wb2[f * GS];
    xr += xv * w1[c2]; xz += xv * w1[64 + c2]; xn += xv * w1[128 + c2];
    hr += hv * w2[c2]; hz += hv * w2[64 + c2]; hn += hv * w2[128 + c2];
  }
  xr += ldf(bihg, c2, flag); xz += ldf(bihg, 64 + c2, flag); xn += ldf(bihg, 128 + c2, flag);
  hr += ldf(bhhg, c2, flag); hz += ldf(bhhg, 64 + c2, flag); hn += ldf(bhhg, 128 + c2, flag);
  float rg = 1.f / (1.f + expf(-(xr + hr)));
  float zg = 1.f / (1.f + expf(-(xz + hz)));
  float nc = tanhf(xn + rg * hn);
  Wout[(j0 + jl) * 64 + c2] = (1.f - zg) * nc + zg * h0r[jl * 64 + c2];
}

// ---- tail stage 1 ----
__global__ void k_g(const float* __restrict__ svec, const float* __restrict__ Wm,
                    const void* gw, const void* gb, float* __restrict__ g,
                    const int* flagp) {
  __shared__ float pooled[64];
  int flag = flagp[0];
  int t = threadIdx.x, w = t >> 6, lane = t & 63;
  if (t < 64) {
    float a = 0.f;
    for (int f = 0; f < 64; f++) a += svec[f] * Wm[f * 64 + t];
    pooled[t] = a * (1.0f / (float)NN);
  }
  __syncthreads();
  int o = blockIdx.x * 4 + w;
  float acc = pooled[lane] * ldf(gw, o * 64 + lane, flag);
  acc = wsum(acc);
  if (lane == 0) g[o] = acc + ldf(gb, o, flag);
}

// ---- tail stage 2 ----
__global__ void k_ln(const float* __restrict__ g, const float* __restrict__ d,
                     const void* lng, const void* lnb, float* __restrict__ lnv,
                     const int* flagp) {
  __shared__ float red[256];
  __shared__ float stats[2];
  int flag = flagp[0];
  int t = threadIdx.x;
  float v0 = g[t], v1 = d[t];
  red[t] = v0 + v1; __syncthreads();
  for (int s = 128; s > 0; s >>= 1) { if (t < s) red[t] += red[t + s]; __syncthreads(); }
  if (t == 0) stats[0] = red[0];
  __syncthreads();
  red[t] = v0 * v0 + v1 * v1; __syncthreads();
  for (int s = 128; s > 0; s >>= 1) { if (t < s) red[t] += red[t + s]; __syncthreads(); }
  if (t == 0) stats[1] = red[0];
  __syncthreads();
  float mu = stats[0] * (1.f / 512.f);
  float var = stats[1] * (1.f / 512.f) - mu * mu;
  float istd = rsqrtf(var + 1e-5f);
  lnv[t]       = (v0 - mu) * istd * ldf(lng, t, flag)       + ldf(lnb, t, flag);
  lnv[t + 256] = (v1 - mu) * istd * ldf(lng, t + 256, flag) + ldf(lnb, t + 256, flag);
}

// ---- tail stage 3 ----
__global__ void k_fuse(const float* __restrict__ lnv, const void* fw, const void* fb,
                       float* __restrict__ h1, const int* flagp) {
  __shared__ float lv[512];
  int flag = flagp[0];
  int t = threadIdx.x, w = t >> 6, lane = t & 63;
  lv[t] = lnv[t]; lv[t + 256] = lnv[t + 256];
  __syncthreads();
  int o = blockIdx.x * 4 + w;
  float acc = 0.f;
  if (flag) {
    uint4 u = *((const uint4*)((const unsigned short*)fw + o * 512) + lane);
    const float* l = &lv[lane * 8];
    acc = bfu(u.x & 0xffff) * l[0] + bfu(u.x >> 16) * l[1]
        + bfu(u.y & 0xffff) * l[2] + bfu(u.y >> 16) * l[3]
        + bfu(u.z & 0xffff) * l[4] + bfu(u.z >> 16) * l[5]
        + bfu(u.w & 0xffff) * l[6] + bfu(u.w >> 16) * l[7];
  } else {
    const float4* fv = (const float4*)((const float*)fw + o * 512);
    float4 a = fv[lane * 2], b = fv[lane * 2 + 1];
    const float* l = &lv[lane * 8];
    acc = a.x * l[0] + a.y * l[1] + a.z * l[2] + a.w * l[3]
        + b.x * l[4] + b.y * l[5] + b.z * l[6] + b.w * l[7];
  }
  acc = wsum(acc);
  if (lane == 0) h1[o] = fmaxf(acc + ldf(fb, o, flag), 0.0f);
}

// ---- tail stage 4 ----
__global__ void k_out(const float* __restrict__ h1, const void* tw, const void* tb,
                      const void* tmw, const void* tmb, void* out, const int* flagp) {
  int flag = flagp[0];
  int t = threadIdx.x, w = t >> 6, lane = t & 63;
  int o = blockIdx.x * 4 + w;
  if (o >= 17) return;
  float acc = 0.f;
  if (o < 16) { for (int k = lane; k < 256; k += 64) acc += h1[k] * ldf(tw, o * 256 + k, flag); }
  else        { for (int k = lane; k < 256; k += 64) acc += h1[k] * ldf(tmw, k, flag); }
  acc = wsum(acc);
  if (lane == 0) {
    float bias = (o < 16) ? ldf(tb, o, flag) : ldf(tmb, 0, flag);
    stf(out, o, acc + bias, flag);
  }
}

extern "C" void kernel_launch(void* const* d_in, const int* in_sizes, int n_in,
                              void* d_out, int out_size, void* d_ws, size_t ws_size,
                              hipStream_t stream) {
  const void* x    = d_in[0];
  const int*  ei   = (const int*)d_in[1];
  const void* docf = d_in[2];
  const void* pw   = d_in[3];
  const void* h0   = d_in[4];
  const void* wih  = d_in[5];
  const void* whh  = d_in[6];
  const void* bih  = d_in[7];
  const void* bhh  = d_in[8];
  const void* gw   = d_in[9];
  const void* gb   = d_in[10];
  const void* dw   = d_in[11];
  const void* db   = d_in[12];
  const void* lng  = d_in[13];
  const void* lnb  = d_in[14];
  const void* fw   = d_in[15];
  const void* fb   = d_in[16];
  const void* tw   = d_in[17];
  const void* tb   = d_in[18];
  const void* tmw  = d_in[19];
  const void* tmb  = d_in[20];

  const int* row = ei;
  const int* col = ei + EE;

  float* wsf = (float*)d_ws;
  int*   wsi = (int*)d_ws;

  // Runtime gate: big path needs BIGPART + ~0.7M words ~= 36.9 MB.
  int big = (ws_size >= (size_t)42 * 1024 * 1024);
  size_t base = big ? (size_t)BIGPART : (size_t)PARTW;

  // runtime offsets (same chain as before, shifted by `base`)
  size_t oHIST  = base;
  size_t oCANDN = oHIST + 65536;
  size_t oS8    = oCANDN + 8;
  size_t oFLAG  = oS8 + 512;
  size_t oTHR   = oFLAG + 8;
  size_t oSV    = oTHR + 8;
  size_t oD     = oSV + 64;
  size_t oDIS   = oD + 256;
  size_t oC     = oDIS + NN;
  size_t oSCORE = oC + NN;
  size_t oCKEY  = oSCORE + NN;
  size_t oCIDX  = oCKEY + 4096;
  size_t oXT    = oCIDX + 4096;
  size_t oWW    = oXT + 4096;
  size_t oG     = oWW + 4096;
  size_t oLNV   = oG + 256;
  size_t oH1    = oLNV + 512;

  hipMemsetAsync(wsi + oCANDN, 0, (size_t)(8 + 512) * 4, stream);
  k_detect<<<1, 256, 0, stream>>>((const unsigned short*)x, wsi + oFLAG);

  if (big) {
    // plain-store partials, no global atomics, no partial-region memsets
    k_hcolB<<<NBC * CCC, HTH, 0, stream>>>(col, (unsigned*)wsi);
    k_redAB<<<NDBLK + 64, 256, 0, stream>>>((const unsigned*)wsi, wsf + oDIS,
                                            docf, dw, db, wsf + oD, wsi + oFLAG);
    k_hrowB<<<NBR * CCR, HTH, 0, stream>>>(row, col, wsf + oDIS, wsf);
    k_redBB<<<NDBLK, 256, 0, stream>>>(wsf, wsf + oDIS, wsf + oC);
  } else {
    // proven R7 fallback: 8-copy atomic merge
    hipMemsetAsync(wsi, 0, (size_t)ZLEN1 * 4, stream);
    k_hcol<<<NBC * CCC, HTH, 0, stream>>>(col, (unsigned*)wsi);
    k_redA<<<NDBLK + 64, 256, 0, stream>>>((const unsigned*)wsi, wsf + oDIS,
                                           docf, dw, db, wsf + oD, wsi + oFLAG);
    hipMemsetAsync(wsi, 0, (size_t)ZLEN2 * 4, stream);
    k_hrow<<<NBR * CCR, HTH, 0, stream>>>(row, col, wsf + oDIS, wsf);
    k_redB<<<NDBLK, 256, 0, stream>>>(wsf, wsf + oDIS, wsf + oC);
  }

  k_x<<<XBLOCKS, 256, 0, stream>>>(x, pw, wsf + oC, wsf + oSCORE,
                                   wsf + oS8, wsi + oFLAG);
  k_hist<<<HB, 1024, 0, stream>>>(wsf + oSCORE, (unsigned*)wsi);
  k_redH<<<HW / 256, 256, 0, stream>>>((const unsigned*)wsi, wsi + oHIST);
  k_thresh<<<1, 256, 0, stream>>>(wsi + oHIST, wsi + oTHR, wsf + oS8, wsf + oSV);
  k_collect<<<NDBLK, 256, 0, stream>>>(wsf + oSCORE, wsi + oTHR, wsi + oCANDN,
                                       (unsigned*)(wsi + oCKEY), wsi + oCIDX);
  k_top<<<1, 1024, 0, stream>>>(wsi + oCANDN, (const unsigned*)(wsi + oCKEY),
                                wsi + oCIDX, x, wsf + oXT, wsi + oFLAG);
  k_gru<<<16, 256, 0, stream>>>(wsf + oXT, h0, wih, whh, bih, bhh, wsf + oWW, wsi + oFLAG);
  k_g<<<64, 256, 0, stream>>>(wsf + oSV, wsf + oWW, gw, gb, wsf + oG, wsi + oFLAG);
  k_ln<<<1, 256, 0, stream>>>(wsf + oG, wsf + oD, lng, lnb, wsf + oLNV, wsi + oFLAG);
  k_fuse<<<64, 256, 0, stream>>>(wsf + oLNV, fw, fb, wsf + oH1, wsi + oFLAG);
  k_out<<<5, 256, 0, stream>>>(wsf + oH1, tw, tb, tmw, tmb, d_out, wsi + oFLAG);
}

// Round 9
// 292.282 us; speedup vs baseline: 1.1130x; 1.0548x over previous
//
#include <hip/hip_runtime.h>
#include <hip/hip_bf16.h>

#define NN    200000
#define EE    3200000
#define DDIMC 768

#define NI4   800000    // EE/4 int4s
#define HTH   1024      // histogram block threads
#define PARTW (25 * 12 * 8192)   // legacy region size (fallback layout)

// ---- fallback (small-ws) path constants: 64KB LDS, atomic 8-copy merge ----
#define BSZC  32768
#define BSHC  15
#define NBC   7
#define CCC   72
#define DEGC  (NBC * (BSZC / 2))
#define BSZR  16384
#define BSHR  14
#define NBR   13
#define CCR   40
#define PARTC (NBR * BSZR)
#define ZLEN1   (8 * DEGC)
#define ZLEN2   (8 * PARTC)

// ---- big-ws path constants: 128KB LDS buckets (gfx950 LDS=160KB/CU), half
// the passes. CC%8==0 keeps same-j blocks on one XCD (L2-shared edge scan).
#define BSZC2 65536     // nodes/bucket, packed 2xu16 -> 32768 u32 = 128KB
#define BSHC2 16
#define NBC2  4         // ceil(200000/65536)
#define CCC2  64        // 4*64 = 256 blocks, 1/CU
#define BSZR2 32768     // float -> 128KB
#define BSHR2 15
#define NBR2  7         // ceil(200000/32768)
#define CCR2  32        // 7*32 = 224 blocks, 1/CU
// Big-path partial region: max(256*32768, 224*32768) = 8388608 words
#define BIGPART (CCR * NBR * BSZR)   // 8519680 words (covers both)

#define NDBLK 782       // ceil(NN/256)
#define XBLOCKS 1024
#define CAPL  4096

#define HB    64        // score-hist partial blocks (NN/HB = 3125 exact)
#define HW    32768     // packed u32 words (2x16-bit counts) = 65536 buckets

// ---- helpers (proven) ----
__device__ __forceinline__ float ldf(const void* p, int i, int bf) {
  if (bf) return __bfloat162float(((const __hip_bfloat16*)p)[i]);
  return ((const float*)p)[i];
}
__device__ __forceinline__ void stf(void* p, int i, float v, int bf) {
  if (bf) ((__hip_bfloat16*)p)[i] = __float2bfloat16(v);
  else ((float*)p)[i] = v;
}
__device__ __forceinline__ float bfu(unsigned u) {   // low 16 bits -> bf16 value
  return __uint_as_float(u << 16);
}
__device__ __forceinline__ float wsum(float v) {
#pragma unroll
  for (int m = 32; m >= 1; m >>= 1) v += __shfl_xor(v, m, 64);
  return v;
}
__device__ __forceinline__ int wsumi(int v) {
#pragma unroll
  for (int m = 32; m >= 1; m >>= 1) v += __shfl_xor(v, m, 64);
  return v;
}
__device__ __forceinline__ unsigned sortkey(float f) {
  unsigned u = __float_as_uint(f);
  return (u & 0x80000000u) ? ~u : (u | 0x80000000u);
}

// ---- dtype detector (proven) ----
__global__ void k_detect(const unsigned short* x16, int* flag) {
  __shared__ int cnt;
  if (threadIdx.x == 0) cnt = 0;
  __syncthreads();
  int ok = 0;
  for (int k = threadIdx.x; k < 512; k += 256) {
    unsigned short u = x16[2 * k];
    int e = (u >> 7) & 0xFF;
    if (u == 0 || (e >= 100 && e <= 150)) ok++;
  }
  atomicAdd(&cnt, ok);
  __syncthreads();
  if (threadIdx.x == 0) flag[0] = (cnt >= 400) ? 1 : 0;
}

// ================= BIG-WS PATH: 128KB LDS buckets, plain stores =============

__global__ void __launch_bounds__(HTH) k_hcolB(const int* __restrict__ col,
                                               unsigned* __restrict__ part) {
  __shared__ unsigned lh[BSZC2 / 2];   // 128KB
  int t = threadIdx.x;
  int b = blockIdx.x / CCC2, j = blockIdx.x % CCC2;
  for (int k = t; k < BSZC2 / 2; k += HTH) lh[k] = 0u;
  __syncthreads();
  int base = b << BSHC2;
  const int4* c4 = (const int4*)col;
  const int stride = CCC2 * HTH;
  for (int i0 = j * HTH + t; i0 < NI4; i0 += 4 * stride) {
    int4 v[4];
#pragma unroll
    for (int u = 0; u < 4; u++) {
      int idx = i0 + u * stride;
      if (idx < NI4) v[u] = c4[idx];
      else { v[u].x = -1; v[u].y = -1; v[u].z = -1; v[u].w = -1; }  // sentinel
    }
#pragma unroll
    for (int u = 0; u < 4; u++) {
      int a0 = v[u].x - base, a1 = v[u].y - base, a2 = v[u].z - base, a3 = v[u].w - base;
      if ((unsigned)a0 < (unsigned)BSZC2) atomicAdd(&lh[a0 >> 1], 1u << ((a0 & 1) * 16));
      if ((unsigned)a1 < (unsigned)BSZC2) atomicAdd(&lh[a1 >> 1], 1u << ((a1 & 1) * 16));
      if ((unsigned)a2 < (unsigned)BSZC2) atomicAdd(&lh[a2 >> 1], 1u << ((a2 & 1) * 16));
      if ((unsigned)a3 < (unsigned)BSZC2) atomicAdd(&lh[a3 >> 1], 1u << ((a3 & 1) * 16));
    }
  }
  __syncthreads();
  unsigned* dst = part + (size_t)blockIdx.x * (BSZC2 / 2);
  for (int k = 4 * t; k < BSZC2 / 2; k += 4 * HTH)
    *(uint4*)&dst[k] = *(const uint4*)&lh[k];
}

__global__ void k_redAB(const unsigned* __restrict__ part, float* __restrict__ dis,
                        const void* docf, const void* dw, const void* db,
                        float* __restrict__ d, const int* flagp) {
  if (blockIdx.x < NDBLK) {
    int i = blockIdx.x * 256 + threadIdx.x;
    if (i < NN) {
      int b = i >> BSHC2;
      int k = (i & (BSZC2 - 1)) >> 1;
      const unsigned* p = part + (size_t)b * CCC2 * (BSZC2 / 2) + k;
      unsigned s = 0;
#pragma unroll 8
      for (int j = 0; j < CCC2; j++) s += p[(size_t)j * (BSZC2 / 2)];
      // packed 2x16 fields: per-node totals << 2^16, no cross-field carry
      int deg = 1 + (int)((s >> ((i & 1) * 16)) & 0xffffu);
      dis[i] = rsqrtf((float)deg);
    }
  } else {
    int flag = flagp[0];
    int o = (blockIdx.x - NDBLK) * 4 + (threadIdx.x >> 6);
    int lane = threadIdx.x & 63;
    float acc = 0.f;
    for (int k = lane; k < DDIMC; k += 64) acc += ldf(docf, k, flag) * ldf(dw, o * DDIMC + k, flag);
    acc = wsum(acc);
    if (lane == 0) d[o] = fmaxf(acc + ldf(db, o, flag), 0.0f);
  }
}

__global__ void __launch_bounds__(HTH) k_hrowB(const int* __restrict__ row, const int* __restrict__ col,
                                               const float* __restrict__ dis,
                                               float* __restrict__ part) {
  __shared__ float lh[BSZR2];          // 128KB
  int t = threadIdx.x;
  int b = blockIdx.x / CCR2, j = blockIdx.x % CCR2;
  for (int k = t; k < BSZR2; k += HTH) lh[k] = 0.f;
  __syncthreads();
  int base = b << BSHR2;
  const int4* r4 = (const int4*)row;
  const int4* c4 = (const int4*)col;
  const int stride = CCR2 * HTH;
  for (int i0 = j * HTH + t; i0 < NI4; i0 += 4 * stride) {
    int4 r[4], c[4];
#pragma unroll
    for (int u = 0; u < 4; u++) {
      int idx = i0 + u * stride;
      if (idx < NI4) { r[u] = r4[idx]; c[u] = c4[idx]; }
      else { r[u].x = -1; r[u].y = -1; r[u].z = -1; r[u].w = -1;    // sentinel
             c[u].x = 0;  c[u].y = 0;  c[u].z = 0;  c[u].w = 0; }
    }
#pragma unroll
    for (int u = 0; u < 4; u++) {
      int a0 = r[u].x - base, a1 = r[u].y - base, a2 = r[u].z - base, a3 = r[u].w - base;
      if ((unsigned)a0 < (unsigned)BSZR2) atomicAdd(&lh[a0], dis[c[u].x]);
      if ((unsigned)a1 < (unsigned)BSZR2) atomicAdd(&lh[a1], dis[c[u].y]);
      if ((unsigned)a2 < (unsigned)BSZR2) atomicAdd(&lh[a2], dis[c[u].z]);
      if ((unsigned)a3 < (unsigned)BSZR2) atomicAdd(&lh[a3], dis[c[u].w]);
    }
  }
  __syncthreads();
  float* dst = part + (size_t)blockIdx.x * BSZR2;
  for (int k = 4 * t; k < BSZR2; k += 4 * HTH)
    *(float4*)&dst[k] = *(const float4*)&lh[k];
}

__global__ void k_redBB(const float* __restrict__ part, const float* __restrict__ dis,
                        float* __restrict__ c) {
  int i = blockIdx.x * 256 + threadIdx.x;
  if (i < NN) {
    int b = i >> BSHR2;
    int k = i & (BSZR2 - 1);
    const float* p = part + (size_t)b * CCR2 * BSZR2 + k;
    float s = 0.f;
#pragma unroll 8
    for (int j = 0; j < CCR2; j++) s += p[(size_t)j * BSZR2];
    float dv = dis[i];
    c[i] = dv * s + dv * dv;
  }
}

// ================= FALLBACK PATH (proven): 64KB LDS, atomic 8-copy merge ====
__global__ void __launch_bounds__(HTH) k_hcol(const int* __restrict__ col,
                                              unsigned* __restrict__ degm) {
  __shared__ unsigned lh[BSZC / 2];
  int t = threadIdx.x;
  int b = blockIdx.x / CCC, j = blockIdx.x % CCC;
  for (int k = t; k < BSZC / 2; k += HTH) lh[k] = 0u;
  __syncthreads();
  int base = b << BSHC;
  const int4* c4 = (const int4*)col;
  const int stride = CCC * HTH;
  for (int i = j * HTH + t; i < NI4; i += 2 * stride) {
    int4 v0 = c4[i];
    int i2 = i + stride;
    int4 v1; v1.x = v1.y = v1.z = v1.w = -1;
    if (i2 < NI4) v1 = c4[i2];
    {
      int a0 = v0.x - base, a1 = v0.y - base, a2 = v0.z - base, a3 = v0.w - base;
      if ((unsigned)a0 < (unsigned)BSZC) atomicAdd(&lh[a0 >> 1], 1u << ((a0 & 1) * 16));
      if ((unsigned)a1 < (unsigned)BSZC) atomicAdd(&lh[a1 >> 1], 1u << ((a1 & 1) * 16));
      if ((unsigned)a2 < (unsigned)BSZC) atomicAdd(&lh[a2 >> 1], 1u << ((a2 & 1) * 16));
      if ((unsigned)a3 < (unsigned)BSZC) atomicAdd(&lh[a3 >> 1], 1u << ((a3 & 1) * 16));
    }
    {
      int a0 = v1.x - base, a1 = v1.y - base, a2 = v1.z - base, a3 = v1.w - base;
      if ((unsigned)a0 < (unsigned)BSZC) atomicAdd(&lh[a0 >> 1], 1u << ((a0 & 1) * 16));
      if ((unsigned)a1 < (unsigned)BSZC) atomicAdd(&lh[a1 >> 1], 1u << ((a1 & 1) * 16));
      if ((unsigned)a2 < (unsigned)BSZC) atomicAdd(&lh[a2 >> 1], 1u << ((a2 & 1) * 16));
      if ((unsigned)a3 < (unsigned)BSZC) atomicAdd(&lh[a3 >> 1], 1u << ((a3 & 1) * 16));
    }
  }
  __syncthreads();
  unsigned* dst = degm + (size_t)(j & 7) * DEGC + (size_t)b * (BSZC / 2);
  for (int k = t; k < BSZC / 2; k += HTH) {
    unsigned v = lh[k];
    if (v) atomicAdd(&dst[k], v);
  }
}

__global__ void k_redA(const unsigned* __restrict__ degm, float* __restrict__ dis,
                       const void* docf, const void* dw, const void* db,
                       float* __restrict__ d, const int* flagp) {
  if (blockIdx.x < NDBLK) {
    int i = blockIdx.x * 256 + threadIdx.x;
    if (i < NN) {
      int sh = (i & 1) * 16;
      int deg = 1;
#pragma unroll
      for (int p = 0; p < 8; p++) {
        unsigned w_ = degm[(size_t)p * DEGC + (i >> 1)];
        deg += (int)((w_ >> sh) & 0xffffu);
      }
      dis[i] = rsqrtf((float)deg);
    }
  } else {
    int flag = flagp[0];
    int o = (blockIdx.x - NDBLK) * 4 + (threadIdx.x >> 6);
    int lane = threadIdx.x & 63;
    float acc = 0.f;
    for (int k = lane; k < DDIMC; k += 64) acc += ldf(docf, k, flag) * ldf(dw, o * DDIMC + k, flag);
    acc = wsum(acc);
    if (lane == 0) d[o] = fmaxf(acc + ldf(db, o, flag), 0.0f);
  }
}

__global__ void __launch_bounds__(HTH) k_hrow(const int* __restrict__ row, const int* __restrict__ col,
                                              const float* __restrict__ dis,
                                              float* __restrict__ partm) {
  __shared__ float lh[BSZR];
  int t = threadIdx.x;
  int b = blockIdx.x / CCR, j = blockIdx.x % CCR;
  for (int k = t; k < BSZR; k += HTH) lh[k] = 0.f;
  __syncthreads();
  int base = b << BSHR;
  const int4* r4 = (const int4*)row;
  const int4* c4 = (const int4*)col;
  const int stride = CCR * HTH;
  for (int i = j * HTH + t; i < NI4; i += 2 * stride) {
    int4 r0 = r4[i];
    int4 c0 = c4[i];
    int i2 = i + stride;
    int4 r1; r1.x = r1.y = r1.z = r1.w = -1;
    int4 c1; c1.x = c1.y = c1.z = c1.w = 0;
    if (i2 < NI4) { r1 = r4[i2]; c1 = c4[i2]; }
    {
      int a0 = r0.x - base, a1 = r0.y - base, a2 = r0.z - base, a3 = r0.w - base;
      if ((unsigned)a0 < (unsigned)BSZR) atomicAdd(&lh[a0], dis[c0.x]);
      if ((unsigned)a1 < (unsigned)BSZR) atomicAdd(&lh[a1], dis[c0.y]);
      if ((unsigned)a2 < (unsigned)BSZR) atomicAdd(&lh[a2], dis[c0.z]);
      if ((unsigned)a3 < (unsigned)BSZR) atomicAdd(&lh[a3], dis[c0.w]);
    }
    {
      int a0 = r1.x - base, a1 = r1.y - base, a2 = r1.z - base, a3 = r1.w - base;
      if ((unsigned)a0 < (unsigned)BSZR) atomicAdd(&lh[a0], dis[c1.x]);
      if ((unsigned)a1 < (unsigned)BSZR) atomicAdd(&lh[a1], dis[c1.y]);
      if ((unsigned)a2 < (unsigned)BSZR) atomicAdd(&lh[a2], dis[c1.z]);
      if ((unsigned)a3 < (unsigned)BSZR) atomicAdd(&lh[a3], dis[c1.w]);
    }
  }
  __syncthreads();
  float* dst = partm + (size_t)(j & 7) * PARTC + (size_t)b * BSZR;
  for (int k = t; k < BSZR; k += HTH) {
    float v = lh[k];
    if (v != 0.f) atomicAdd(&dst[k], v);
  }
}

__global__ void k_redB(const float* __restrict__ partm, const float* __restrict__ dis,
                       float* __restrict__ c) {
  int i = blockIdx.x * 256 + threadIdx.x;
  if (i < NN) {
    float s = 0.f;
#pragma unroll
    for (int p = 0; p < 8; p++) s += partm[(size_t)p * PARTC + i];
    float dv = dis[i];
    c[i] = dv * s + dv * dv;
  }
}

// ---- fused x pass (proven R2): pure stream, score + column accumulator ----
__global__ void k_x(const void* x, const void* pw, const float* __restrict__ c,
                    float* __restrict__ score,
                    float* __restrict__ s8, const int* flagp) {
  __shared__ float sred[4][64];
  int flag = flagp[0];
  int t = threadIdx.x;
  int lane = t & 63;
  int w = t >> 6;
  int wid = (blockIdx.x * 256 + t) >> 6;
  int nw = (gridDim.x * 256) >> 6;

  if (flag) {
    int g  = lane >> 3;
    int c0 = (lane & 7) * 8;
    float pwv[8];
#pragma unroll
    for (int j = 0; j < 8; j++) pwv[j] = ldf(pw, c0 + j, 1);
    float s = 0.f;
#pragma unroll
    for (int j = 0; j < 8; j++) s += pwv[j] * pwv[j];
    float inv = 1.0f / sqrtf(wsum(s) * 0.125f);
    float sacc[8] = {0.f, 0.f, 0.f, 0.f, 0.f, 0.f, 0.f, 0.f};
    const uint4* x4 = (const uint4*)x;
    for (int r0 = wid * 8; r0 < NN; r0 += nw * 8) {
      int r = r0 + g;
      uint4 u = x4[r * 8 + (lane & 7)];
      float xv[8] = { bfu(u.x & 0xffff), bfu(u.x >> 16),
                      bfu(u.y & 0xffff), bfu(u.y >> 16),
                      bfu(u.z & 0xffff), bfu(u.z >> 16),
                      bfu(u.w & 0xffff), bfu(u.w >> 16) };
      float dot = 0.f;
#pragma unroll
      for (int j = 0; j < 8; j++) dot += xv[j] * pwv[j];
      dot += __shfl_xor(dot, 1, 64);
      dot += __shfl_xor(dot, 2, 64);
      dot += __shfl_xor(dot, 4, 64);
      float cr = c[r];
#pragma unroll
      for (int j = 0; j < 8; j++) sacc[j] += cr * xv[j];
      if ((lane & 7) == 0) score[r] = dot * inv;
    }
#pragma unroll
    for (int j = 0; j < 8; j++) {
      sacc[j] += __shfl_xor(sacc[j], 8, 64);
      sacc[j] += __shfl_xor(sacc[j], 16, 64);
      sacc[j] += __shfl_xor(sacc[j], 32, 64);
    }
    if (lane < 8) {
#pragma unroll
      for (int j = 0; j < 8; j++) sred[w][lane * 8 + j] = sacc[j];
    }
  } else {
    int g  = lane >> 4;
    int c0 = (lane & 15) * 4;
    float pwv[4];
#pragma unroll
    for (int j = 0; j < 4; j++) pwv[j] = ((const float*)pw)[c0 + j];
    float s = 0.f;
#pragma unroll
    for (int j = 0; j < 4; j++) s += pwv[j] * pwv[j];
    float inv = 1.0f / sqrtf(wsum(s) * (1.f / 16.f));
    float sacc[4] = {0.f, 0.f, 0.f, 0.f};
    const float4* x4 = (const float4*)x;
    for (int r0 = wid * 4; r0 < NN; r0 += nw * 4) {
      int r = r0 + g;
      float4 v = x4[r * 16 + (lane & 15)];
      float xv[4] = { v.x, v.y, v.z, v.w };
      float dot = 0.f;
#pragma unroll
      for (int j = 0; j < 4; j++) dot += xv[j] * pwv[j];
      dot += __shfl_xor(dot, 1, 64);
      dot += __shfl_xor(dot, 2, 64);
      dot += __shfl_xor(dot, 4, 64);
      dot += __shfl_xor(dot, 8, 64);
      float cr = c[r];
#pragma unroll
      for (int j = 0; j < 4; j++) sacc[j] += cr * xv[j];
      if ((lane & 15) == 0) score[r] = dot * inv;
    }
#pragma unroll
    for (int j = 0; j < 4; j++) {
      sacc[j] += __shfl_xor(sacc[j], 16, 64);
      sacc[j] += __shfl_xor(sacc[j], 32, 64);
    }
    if (lane < 16) {
#pragma unroll
      for (int j = 0; j < 4; j++) sred[w][lane * 4 + j] = sacc[j];
    }
  }
  __syncthreads();
  if (w == 0)
    atomicAdd(&s8[(blockIdx.x & 7) * 64 + lane],
              sred[0][lane] + sred[1][lane] + sred[2][lane] + sred[3][lane]);
}

// ---- LDS-privatized full-resolution score histogram (proven R2) ----
__global__ void __launch_bounds__(1024) k_hist(const float* __restrict__ score,
                                               unsigned* __restrict__ part) {
  __shared__ unsigned lh[HW];
  int t = threadIdx.x;
  for (int k = t; k < HW; k += 1024) lh[k] = 0u;
  __syncthreads();
  int r0 = blockIdx.x * (NN / HB);
  int r1 = r0 + (NN / HB);
  for (int i = r0 + t; i < r1; i += 1024) {
    unsigned b = sortkey(score[i]) >> 16;
    atomicAdd(&lh[b >> 1], 1u << ((b & 1) * 16));
  }
  __syncthreads();
  unsigned* dst = part + (size_t)blockIdx.x * HW;
  for (int k = t; k < HW; k += 1024) dst[k] = lh[k];
}

// ---- sum HB packed partials -> hist (proven R2) ----
__global__ void k_redH(const unsigned* __restrict__ part, int* __restrict__ hist) {
  int w = blockIdx.x * 256 + threadIdx.x;
  unsigned lo = 0, hi = 0;
  for (int b = 0; b < HB; b++) {
    unsigned v = part[(size_t)b * HW + w];
    lo += v & 0xffffu;
    hi += v >> 16;
  }
  hist[2 * w]     = (int)lo;
  hist[2 * w + 1] = (int)hi;
}

// ---- threshold (proven) ----
__global__ void k_thresh(const int* __restrict__ hist, int* __restrict__ thrB,
                         const float* __restrict__ s8, float* __restrict__ svec) {
  __shared__ int part[256];
  __shared__ int segl[256];
  __shared__ int res2[2];
  int t = threadIdx.x, w = t >> 6, lane = t & 63;
  if (t < 64) {
    float a = 0.f;
    for (int r = 0; r < 8; r++) a += s8[r * 64 + t];
    svec[t] = a;
  }
  for (int m = w; m < 256; m += 4) {
    const int* hb = &hist[m * 256];
    int a = hb[lane] + hb[lane + 64] + hb[lane + 128] + hb[lane + 192];
    a = wsumi(a);
    if (lane == 0) part[m] = a;
  }
  __syncthreads();
  if (t == 0) {
    int acc = 0, seg = 0, above = 0;
    for (int b = 255; b >= 0; b--) {
      if (acc + part[b] >= 64) { seg = b; above = acc; break; }
      acc += part[b];
    }
    res2[0] = seg; res2[1] = above;
  }
  __syncthreads();
  segl[t] = hist[res2[0] * 256 + t];
  __syncthreads();
  if (t == 0) {
    int acc = res2[1], B = res2[0] * 256;
    for (int j = 255; j >= 0; j--) {
      acc += segl[j];
      if (acc >= 64) { B = res2[0] * 256 + j; break; }
    }
    thrB[0] = B;
  }
}

// ---- collect (proven) ----
__global__ void k_collect(const float* __restrict__ score, const int* __restrict__ thrB,
                          int* __restrict__ candn, unsigned* __restrict__ ckey,
                          int* __restrict__ cidx) {
  int i = blockIdx.x * blockDim.x + threadIdx.x;
  if (i >= NN) return;
  unsigned u = sortkey(score[i]);
  if ((int)(u >> 16) >= thrB[0]) {
    int p = atomicAdd(candn, 1);
    if (p < CAPL) { ckey[p] = u; cidx[p] = i; }
  }
}

// ---- top-64 (1024 threads) ----
__global__ void __launch_bounds__(1024) k_top(const int* __restrict__ candn,
                      const unsigned* __restrict__ ckey,
                      const int* __restrict__ cidx, const void* x,
                      float* __restrict__ xt, const int* flagp) {
  __shared__ unsigned long long keys[CAPL];
  __shared__ int perm[64];
  __shared__ float ts[64];
  int flag = flagp[0];
  int t = threadIdx.x;
  int M = candn[0];
  if (M > CAPL) M = CAPL;
  for (int j = t; j < M; j += 1024)
    keys[j] = (((unsigned long long)ckey[j]) << 32) |
              (unsigned long long)(0xFFFFFFFFu - (unsigned)cidx[j]);
  __syncthreads();
  for (int j = t; j < M; j += 1024) {
    unsigned long long k = keys[j];
    int rank = 0;
    for (int i = 0; i < M; i++) rank += (keys[i] > k) ? 1 : 0;
    if (rank < 64) {
      unsigned ku = (unsigned)(k >> 32);
      unsigned idx = 0xFFFFFFFFu - (unsigned)(k & 0xFFFFFFFFu);
      perm[rank] = (int)idx;
      unsigned bits = (ku & 0x80000000u) ? (ku ^ 0x80000000u) : ~ku;
      ts[rank] = tanhf(__uint_as_float(bits));
    }
  }
  __syncthreads();
  for (int q = t; q < 4096; q += 1024) {
    int j = q >> 6, f = q & 63;
    xt[q] = ldf(x, perm[j] * 64 + f, flag) * ts[j];
  }
}

// ---- GRU (proven round-0 rework): coalesced staging, LDS-side transpose ----
#define GS 193
__device__ __forceinline__ void stage_w(const void* src, float* dst, int flag, int t) {
  if (flag) {
    const uint4* s4 = (const uint4*)src;
    for (int k = t; k < 1536; k += 256) {
      uint4 u = s4[k];
      int e = k << 3; int o = e >> 6, f = e & 63;
      float* d = &dst[f * GS + o];
      d[0]      = bfu(u.x & 0xffff); d[GS]     = bfu(u.x >> 16);
      d[2 * GS] = bfu(u.y & 0xffff); d[3 * GS] = bfu(u.y >> 16);
      d[4 * GS] = bfu(u.z & 0xffff); d[5 * GS] = bfu(u.z >> 16);
      d[6 * GS] = bfu(u.w & 0xffff); d[7 * GS] = bfu(u.w >> 16);
    }
  } else {
    const float4* s4 = (const float4*)src;
    for (int k = t; k < 3072; k += 256) {
      float4 v = s4[k];
      int e = k << 2; int o = e >> 6, f = e & 63;
      float* d = &dst[f * GS + o];
      d[0] = v.x; d[GS] = v.y; d[2 * GS] = v.z; d[3 * GS] = v.w;
    }
  }
}

__global__ void k_gru(const float* __restrict__ xt, const void* h0g, const void* wihg,
                      const void* whhg, const void* bihg, const void* bhhg,
                      float* __restrict__ Wout, const int* flagp) {
  __shared__ float wb1[64 * GS];
  __shared__ float wb2[64 * GS];
  __shared__ float xtr[256];
  __shared__ float h0r[256];
  int flag = flagp[0];
  int t = threadIdx.x;
  int j0 = blockIdx.x * 4;
  { int jj = t >> 6, f = t & 63;
    xtr[t] = xt[(j0 + jj) * 64 + f];
    h0r[t] = ldf(h0g, (j0 + jj) * 64 + f, flag); }
  stage_w(wihg, wb1, flag, t);
  stage_w(whhg, wb2, flag, t);
  __syncthreads();
  int jl = t >> 6, c2 = t & 63;
  float xr = 0, xz = 0, xn = 0, hr = 0, hz = 0, hn = 0;
#pragma unroll 4
  for (int f = 0; f < 64; f++) {
    float xv = xtr[jl * 64 + f];
    float hv = h0r[jl * 64 + f];
    const float* w1 = &wb1[f * GS];
    const float* w2 = &wb2[f * GS];
    xr += xv * w1[c2]; xz += xv * w1[64 + c2]; xn += xv * w1[128 + c2];
    hr += hv * w2[c2]; hz += hv * w2[64 + c2]; hn += hv * w2[128 + c2];
  }
  xr += ldf(bihg, c2, flag); xz += ldf(bihg, 64 + c2, flag); xn += ldf(bihg, 128 + c2, flag);
  hr += ldf(bhhg, c2, flag); hz += ldf(bhhg, 64 + c2, flag); hn += ldf(bhhg, 128 + c2, flag);
  float rg = 1.f / (1.f + expf(-(xr + hr)));
  float zg = 1.f / (1.f + expf(-(xz + hz)));
  float nc = tanhf(xn + rg * hn);
  Wout[(j0 + jl) * 64 + c2] = (1.f - zg) * nc + zg * h0r[jl * 64 + c2];
}

// ---- tail stage 1 ----
__global__ void k_g(const float* __restrict__ svec, const float* __restrict__ Wm,
                    const void* gw, const void* gb, float* __restrict__ g,
                    const int* flagp) {
  __shared__ float pooled[64];
  int flag = flagp[0];
  int t = threadIdx.x, w = t >> 6, lane = t & 63;
  if (t < 64) {
    float a = 0.f;
    for (int f = 0; f < 64; f++) a += svec[f] * Wm[f * 64 + t];
    pooled[t] = a * (1.0f / (float)NN);
  }
  __syncthreads();
  int o = blockIdx.x * 4 + w;
  float acc = pooled[lane] * ldf(gw, o * 64 + lane, flag);
  acc = wsum(acc);
  if (lane == 0) g[o] = acc + ldf(gb, o, flag);
}

// ---- tail stage 2 ----
__global__ void k_ln(const float* __restrict__ g, const float* __restrict__ d,
                     const void* lng, const void* lnb, float* __restrict__ lnv,
                     const int* flagp) {
  __shared__ float red[256];
  __shared__ float stats[2];
  int flag = flagp[0];
  int t = threadIdx.x;
  float v0 = g[t], v1 = d[t];
  red[t] = v0 + v1; __syncthreads();
  for (int s = 128; s > 0; s >>= 1) { if (t < s) red[t] += red[t + s]; __syncthreads(); }
  if (t == 0) stats[0] = red[0];
  __syncthreads();
  red[t] = v0 * v0 + v1 * v1; __syncthreads();
  for (int s = 128; s > 0; s >>= 1) { if (t < s) red[t] += red[t + s]; __syncthreads(); }
  if (t == 0) stats[1] = red[0];
  __syncthreads();
  float mu = stats[0] * (1.f / 512.f);
  float var = stats[1] * (1.f / 512.f) - mu * mu;
  float istd = rsqrtf(var + 1e-5f);
  lnv[t]       = (v0 - mu) * istd * ldf(lng, t, flag)       + ldf(lnb, t, flag);
  lnv[t + 256] = (v1 - mu) * istd * ldf(lng, t + 256, flag) + ldf(lnb, t + 256, flag);
}

// ---- tail stage 3 ----
__global__ void k_fuse(const float* __restrict__ lnv, const void* fw, const void* fb,
                       float* __restrict__ h1, const int* flagp) {
  __shared__ float lv[512];
  int flag = flagp[0];
  int t = threadIdx.x, w = t >> 6, lane = t & 63;
  lv[t] = lnv[t]; lv[t + 256] = lnv[t + 256];
  __syncthreads();
  int o = blockIdx.x * 4 + w;
  float acc = 0.f;
  if (flag) {
    uint4 u = *((const uint4*)((const unsigned short*)fw + o * 512) + lane);
    const float* l = &lv[lane * 8];
    acc = bfu(u.x & 0xffff) * l[0] + bfu(u.x >> 16) * l[1]
        + bfu(u.y & 0xffff) * l[2] + bfu(u.y >> 16) * l[3]
        + bfu(u.z & 0xffff) * l[4] + bfu(u.z >> 16) * l[5]
        + bfu(u.w & 0xffff) * l[6] + bfu(u.w >> 16) * l[7];
  } else {
    const float4* fv = (const float4*)((const float*)fw + o * 512);
    float4 a = fv[lane * 2], b = fv[lane * 2 + 1];
    const float* l = &lv[lane * 8];
    acc = a.x * l[0] + a.y * l[1] + a.z * l[2] + a.w * l[3]
        + b.x * l[4] + b.y * l[5] + b.z * l[6] + b.w * l[7];
  }
  acc = wsum(acc);
  if (lane == 0) h1[o] = fmaxf(acc + ldf(fb, o, flag), 0.0f);
}

// ---- tail stage 4 ----
__global__ void k_out(const float* __restrict__ h1, const void* tw, const void* tb,
                      const void* tmw, const void* tmb, void* out, const int* flagp) {
  int flag = flagp[0];
  int t = threadIdx.x, w = t >> 6, lane = t & 63;
  int o = blockIdx.x * 4 + w;
  if (o >= 17) return;
  float acc = 0.f;
  if (o < 16) { for (int k = lane; k < 256; k += 64) acc += h1[k] * ldf(tw, o * 256 + k, flag); }
  else        { for (int k = lane; k < 256; k += 64) acc += h1[k] * ldf(tmw, k, flag); }
  acc = wsum(acc);
  if (lane == 0) {
    float bias = (o < 16) ? ldf(tb, o, flag) : ldf(tmb, 0, flag);
    stf(out, o, acc + bias, flag);
  }
}

extern "C" void kernel_launch(void* const* d_in, const int* in_sizes, int n_in,
                              void* d_out, int out_size, void* d_ws, size_t ws_size,
                              hipStream_t stream) {
  const void* x    = d_in[0];
  const int*  ei   = (const int*)d_in[1];
  const void* docf = d_in[2];
  const void* pw   = d_in[3];
  const void* h0   = d_in[4];
  const void* wih  = d_in[5];
  const void* whh  = d_in[6];
  const void* bih  = d_in[7];
  const void* bhh  = d_in[8];
  const void* gw   = d_in[9];
  const void* gb   = d_in[10];
  const void* dw   = d_in[11];
  const void* db   = d_in[12];
  const void* lng  = d_in[13];
  const void* lnb  = d_in[14];
  const void* fw   = d_in[15];
  const void* fb   = d_in[16];
  const void* tw   = d_in[17];
  const void* tb   = d_in[18];
  const void* tmw  = d_in[19];
  const void* tmb  = d_in[20];

  const int* row = ei;
  const int* col = ei + EE;

  float* wsf = (float*)d_ws;
  int*   wsi = (int*)d_ws;

  // Runtime gate: big path needs BIGPART + ~0.7M words ~= 36.9 MB.
  int big = (ws_size >= (size_t)42 * 1024 * 1024);
  size_t base = big ? (size_t)BIGPART : (size_t)PARTW;

  // runtime offsets (same chain as before, shifted by `base`)
  size_t oHIST  = base;
  size_t oCANDN = oHIST + 65536;
  size_t oS8    = oCANDN + 8;
  size_t oFLAG  = oS8 + 512;
  size_t oTHR   = oFLAG + 8;
  size_t oSV    = oTHR + 8;
  size_t oD     = oSV + 64;
  size_t oDIS   = oD + 256;
  size_t oC     = oDIS + NN;
  size_t oSCORE = oC + NN;
  size_t oCKEY  = oSCORE + NN;
  size_t oCIDX  = oCKEY + 4096;
  size_t oXT    = oCIDX + 4096;
  size_t oWW    = oXT + 4096;
  size_t oG     = oWW + 4096;
  size_t oLNV   = oG + 256;
  size_t oH1    = oLNV + 512;

  hipMemsetAsync(wsi + oCANDN, 0, (size_t)(8 + 512) * 4, stream);
  k_detect<<<1, 256, 0, stream>>>((const unsigned short*)x, wsi + oFLAG);

  if (big) {
    // 128KB-LDS buckets: half the passes, plain-store partials, no atomics
    k_hcolB<<<NBC2 * CCC2, HTH, 0, stream>>>(col, (unsigned*)wsi);
    k_redAB<<<NDBLK + 64, 256, 0, stream>>>((const unsigned*)wsi, wsf + oDIS,
                                            docf, dw, db, wsf + oD, wsi + oFLAG);
    k_hrowB<<<NBR2 * CCR2, HTH, 0, stream>>>(row, col, wsf + oDIS, wsf);
    k_redBB<<<NDBLK, 256, 0, stream>>>(wsf, wsf + oDIS, wsf + oC);
  } else {
    // proven fallback: 64KB LDS, 8-copy atomic merge
    hipMemsetAsync(wsi, 0, (size_t)ZLEN1 * 4, stream);
    k_hcol<<<NBC * CCC, HTH, 0, stream>>>(col, (unsigned*)wsi);
    k_redA<<<NDBLK + 64, 256, 0, stream>>>((const unsigned*)wsi, wsf + oDIS,
                                           docf, dw, db, wsf + oD, wsi + oFLAG);
    hipMemsetAsync(wsi, 0, (size_t)ZLEN2 * 4, stream);
    k_hrow<<<NBR * CCR, HTH, 0, stream>>>(row, col, wsf + oDIS, wsf);
    k_redB<<<NDBLK, 256, 0, stream>>>(wsf, wsf + oDIS, wsf + oC);
  }

  k_x<<<XBLOCKS, 256, 0, stream>>>(x, pw, wsf + oC, wsf + oSCORE,
                                   wsf + oS8, wsi + oFLAG);
  k_hist<<<HB, 1024, 0, stream>>>(wsf + oSCORE, (unsigned*)wsi);
  k_redH<<<HW / 256, 256, 0, stream>>>((const unsigned*)wsi, wsi + oHIST);
  k_thresh<<<1, 256, 0, stream>>>(wsi + oHIST, wsi + oTHR, wsf + oS8, wsf + oSV);
  k_collect<<<NDBLK, 256, 0, stream>>>(wsf + oSCORE, wsi + oTHR, wsi + oCANDN,
                                       (unsigned*)(wsi + oCKEY), wsi + oCIDX);
  k_top<<<1, 1024, 0, stream>>>(wsi + oCANDN, (const unsigned*)(wsi + oCKEY),
                                wsi + oCIDX, x, wsf + oXT, wsi + oFLAG);
  k_gru<<<16, 256, 0, stream>>>(wsf + oXT, h0, wih, whh, bih, bhh, wsf + oWW, wsi + oFLAG);
  k_g<<<64, 256, 0, stream>>>(wsf + oSV, wsf + oWW, gw, gb, wsf + oG, wsi + oFLAG);
  k_ln<<<1, 256, 0, stream>>>(wsf + oG, wsf + oD, lng, lnb, wsf + oLNV, wsi + oFLAG);
  k_fuse<<<64, 256, 0, stream>>>(wsf + oLNV, fw, fb, wsf + oH1, wsi + oFLAG);
  k_out<<<5, 256, 0, stream>>>(wsf + oH1, tw, tb, tmw, tmb, d_out, wsi + oFLAG);
}